// Round 1
// baseline (1721.662 us; speedup 1.0000x reference)
//
#include <hip/hip_runtime.h>
#include <cmath>

// ---------------------------------------------------------------------------
// DynamicProbSparseAttention: B=4, L=8192, D=1024, H=16, dk=64
// Strategy:
//   - bf16 MFMA GEMM for Q,K,V (dominant cost, 206 GFLOP)
//   - approx scores from bf16 Q -> top-16 candidate prefilter
//   - exact fp64 rescore of candidates from original f32 x,wq -> top-10 + u
//   - sparse attention for <=10 rows per (b,h), chunked online softmax
//   - output = broadcast bo + sparse scatter of (attn_out @ wo_head.T)
// ---------------------------------------------------------------------------

typedef short     s16x8 __attribute__((ext_vector_type(8)));
typedef unsigned short u16x8 __attribute__((ext_vector_type(8)));
typedef float     f32x4 __attribute__((ext_vector_type(4)));

__device__ __forceinline__ unsigned short f2bf(float f) {
    unsigned u = __float_as_uint(f);
    u += 0x7fffu + ((u >> 16) & 1u);   // round-to-nearest-even
    return (unsigned short)(u >> 16);
}
__device__ __forceinline__ float bf2f(unsigned short s) {
    return __uint_as_float(((unsigned)s) << 16);
}

__device__ __forceinline__ void async16(const void* g, void* l) {
    __builtin_amdgcn_global_load_lds(
        (const __attribute__((address_space(1))) void*)g,
        (__attribute__((address_space(3))) void*)l, 16, 0, 0);
}

// ---------------- convert kernels ----------------
__global__ void k_conv_x(const float* __restrict__ x, unsigned short* __restrict__ xb) {
    size_t i = (size_t)blockIdx.x * 256 + threadIdx.x;    // 8388608 float4s
    float4 v = ((const float4*)x)[i];
    ushort4 o; o.x = f2bf(v.x); o.y = f2bf(v.y); o.z = f2bf(v.z); o.w = f2bf(v.w);
    ((ushort4*)xb)[i] = o;
}

__global__ void k_conv_w(const float* __restrict__ wq, const float* __restrict__ wk,
                         const float* __restrict__ wv, unsigned short* __restrict__ wb) {
    size_t i = (size_t)blockIdx.x * 256 + threadIdx.x;    // 786432 float4s
    size_t wsel = i >> 18;                                // 262144 float4 per weight
    size_t rem  = i & 262143;
    const float* src = wsel == 0 ? wq : (wsel == 1 ? wk : wv);
    float4 v = ((const float4*)src)[rem];
    ushort4 o; o.x = f2bf(v.x); o.y = f2bf(v.y); o.z = f2bf(v.z); o.w = f2bf(v.w);
    ((ushort4*)wb)[i] = o;
}

// ---------------- fused QKV GEMM (C = x @ W^T + b), bf16 MFMA ----------------
// grid: 256 m-tiles * 3 weights * 8 n-tiles = 6144 blocks, 256 threads.
__global__ __launch_bounds__(256) void k_gemm_qkv(
    const unsigned short* __restrict__ xb, const unsigned short* __restrict__ wb,
    const float* __restrict__ bq, const float* __restrict__ bk, const float* __restrict__ bv,
    unsigned short* __restrict__ Qb, unsigned short* __restrict__ Kb, unsigned short* __restrict__ Vb)
{
    __shared__ unsigned short As[128 * 32];
    __shared__ unsigned short Bs[128 * 32];
    int bid = blockIdx.x;
    int mt = bid / 24, rem = bid % 24, wsel = rem >> 3, nt = rem & 7;
    const unsigned short* wbase = wb + ((size_t)wsel << 20) + ((size_t)nt * 128) * 1024;
    const float* bias = wsel == 0 ? bq : (wsel == 1 ? bk : bv);
    unsigned short* outp = wsel == 0 ? Qb : (wsel == 1 ? Kb : Vb);
    int tid = threadIdx.x, wave = tid >> 6, lane = tid & 63;
    int ml = lane & 15, quad = lane >> 4, wm = wave >> 1, wn = wave & 1;
    int lr = lane >> 2, lc = lane & 3;
    const unsigned short* xbase = xb + ((size_t)mt * 128) * 1024;

    f32x4 acc[4][4] = {};
    for (int k0 = 0; k0 < 1024; k0 += 32) {
#pragma unroll
        for (int s = 0; s < 2; ++s) {
            int seg = wave * 2 + s;
            int row = seg * 16 + lr;
            async16(xbase + (size_t)row * 1024 + k0 + lc * 8, &As[seg * 512]);
            async16(wbase + (size_t)row * 1024 + k0 + lc * 8, &Bs[seg * 512]);
        }
        __builtin_amdgcn_s_waitcnt(0);
        __syncthreads();
        s16x8 a[4], b[4];
#pragma unroll
        for (int i = 0; i < 4; ++i) a[i] = *(const s16x8*)&As[(wm * 64 + i * 16 + ml) * 32 + quad * 8];
#pragma unroll
        for (int j = 0; j < 4; ++j) b[j] = *(const s16x8*)&Bs[(wn * 64 + j * 16 + ml) * 32 + quad * 8];
#pragma unroll
        for (int i = 0; i < 4; ++i)
#pragma unroll
            for (int j = 0; j < 4; ++j)
                acc[i][j] = __builtin_amdgcn_mfma_f32_16x16x32_bf16(a[i], b[j], acc[i][j], 0, 0, 0);
        __syncthreads();
    }
    // epilogue: C layout col=lane&15, row=quad*4+reg
#pragma unroll
    for (int i = 0; i < 4; ++i) {
        int grow0 = mt * 128 + wm * 64 + i * 16 + quad * 4;
#pragma unroll
        for (int j = 0; j < 4; ++j) {
            int gcol = nt * 128 + wn * 64 + j * 16 + ml;
            float bvv = bias[gcol];
#pragma unroll
            for (int r = 0; r < 4; ++r)
                outp[(size_t)(grow0 + r) * 1024 + gcol] = f2bf(acc[i][j][r] + bvv);
        }
    }
}

// ---------------- per-(b,h,l) sparsity scores from bf16 Q ----------------
__global__ void k_score(const unsigned short* __restrict__ Qb, float* __restrict__ scores) {
    int gid = blockIdx.x * 256 + threadIdx.x;   // 524288 items
    int r = gid >> 4, h = gid & 15;
    const u16x8* qp = (const u16x8*)(Qb + (size_t)r * 1024 + h * 64);
    float q[64];
#pragma unroll
    for (int i = 0; i < 8; ++i) {
        u16x8 v = qp[i];
#pragma unroll
        for (int e = 0; e < 8; ++e) q[i * 8 + e] = bf2f(v[e]);
    }
    float m = -1e30f;
#pragma unroll
    for (int i = 0; i < 64; ++i) m = fmaxf(m, q[i]);
    float sum = 0.f, sumsq = 0.f, S = 0.f;
#pragma unroll
    for (int i = 0; i < 64; ++i) { sum += q[i]; sumsq += q[i] * q[i]; S += expf(q[i] - m); }
    float ent = 0.f;
#pragma unroll
    for (int i = 0; i < 64; ++i) { float p = expf(q[i] - m) / S; ent -= p * logf(p + 1e-9f); }
    float mean = sum * (1.f / 64.f);
    float var = 0.f;
#pragma unroll
    for (int i = 0; i < 64; ++i) { float d = q[i] - mean; var += d * d; }
    var *= (1.f / 63.f);
    float sc = 0.5f * sqrtf(sumsq) + 0.3f * ent + 0.2f * var;
    int b = r >> 13, l = r & 8191;
    scores[(size_t)((b << 4) + h) * 8192 + l] = sc;
}

// ---------------- u[b] from head-0 score stats ----------------
__global__ void k_stats(const float* __restrict__ scores, int* __restrict__ u) {
    int b = blockIdx.x, t = threadIdx.x;
    const float* s = scores + (size_t)(b * 16) * 8192;    // head 0
    __shared__ double red[256];
    double a0 = 0;
    for (int i = t; i < 8192; i += 256) a0 += (double)s[i];
    red[t] = a0; __syncthreads();
    for (int st = 128; st > 0; st >>= 1) { if (t < st) red[t] += red[t + st]; __syncthreads(); }
    double mean = red[0] / 8192.0;
    __syncthreads();
    double a1 = 0;
    for (int i = t; i < 8192; i += 256) { double d = (double)s[i] - mean; a1 += d * d; }
    red[t] = a1; __syncthreads();
    for (int st = 128; st > 0; st >>= 1) { if (t < st) red[t] += red[t + st]; __syncthreads(); }
    if (t == 0) {
        double sd = sqrt(red[0] / 8191.0);
        double ratio = sd / (mean + 1e-6) * 10.0;
        int f = (int)rint(ratio);                 // round-half-even, matches jnp.round
        f = f < 3 ? 3 : (f > 10 ? 10 : f);
        u[b] = f;
    }
}

// ---------------- top-16 prefilter + exact fp64 rescore + top-10 select ----------------
__global__ void k_topk(const float* __restrict__ scores,
                       const float* __restrict__ x, const float* __restrict__ wq,
                       const float* __restrict__ bq,
                       int* __restrict__ sel, float* __restrict__ selq)
{
    int pair = blockIdx.x; int b = pair >> 4, h = pair & 15;
    int t = threadIdx.x;
    __shared__ float  s_lds[8192];
    __shared__ float  rv[256];
    __shared__ int    ri[256];
    __shared__ int    cand[16];
    __shared__ double qrow[64];
    __shared__ double cscore[16];
    __shared__ float  cq[16][64];
    __shared__ float  xrow[1024];
    __shared__ double dred[256];
    __shared__ int    order[16];

    const float* sp = scores + (size_t)pair * 8192;
    for (int i = t; i < 8192; i += 256) s_lds[i] = sp[i];
    __syncthreads();

    // iterative argmax x16 (tie -> lower index, matching top_k stability)
    for (int it = 0; it < 16; ++it) {
        float bv = -1e30f; int bi = 0x7fffffff;
        for (int i = t; i < 8192; i += 256) {
            float v = s_lds[i];
            if (v > bv || (v == bv && i < bi)) { bv = v; bi = i; }
        }
        rv[t] = bv; ri[t] = bi; __syncthreads();
        for (int st = 128; st > 0; st >>= 1) {
            if (t < st) {
                float ov = rv[t + st]; int oi = ri[t + st];
                if (ov > rv[t] || (ov == rv[t] && oi < ri[t])) { rv[t] = ov; ri[t] = oi; }
            }
            __syncthreads();
        }
        if (t == 0) { cand[it] = ri[0]; s_lds[ri[0]] = -1e30f; }
        __syncthreads();
    }

    // exact fp64 rescore from original f32 inputs
    for (int c = 0; c < 16; ++c) {
        int l = cand[c];
        const float* xr = x + ((size_t)b * 8192 + l) * 1024;
        for (int i = t; i < 1024; i += 256) xrow[i] = xr[i];
        __syncthreads();
        int d = t >> 2, ks = t & 3;    // d in [0,64), k-slice of 256
        const float* wr = wq + (size_t)(h * 64 + d) * 1024 + ks * 256;
        const float* xs = xrow + ks * 256;
        double p = 0;
        for (int k = 0; k < 256; k += 4) {
            float4 w4 = *(const float4*)(wr + k);
            float4 x4 = *(const float4*)(xs + k);
            p += (double)w4.x * x4.x + (double)w4.y * x4.y +
                 (double)w4.z * x4.z + (double)w4.w * x4.w;
        }
        dred[t] = p; __syncthreads();
        if ((t & 3) == 0) {
            int dd = t >> 2;
            qrow[dd] = dred[t] + dred[t + 1] + dred[t + 2] + dred[t + 3] + (double)bq[h * 64 + dd];
        }
        __syncthreads();
        if (t < 64) cq[c][t] = (float)qrow[t];
        if (t == 0) {
            double m = -1e300, sum = 0, sumsq = 0;
            for (int i = 0; i < 64; ++i) { double q = qrow[i]; if (q > m) m = q; sum += q; sumsq += q * q; }
            double S = 0;
            for (int i = 0; i < 64; ++i) S += exp(qrow[i] - m);
            double ent = 0;
            for (int i = 0; i < 64; ++i) { double pp = exp(qrow[i] - m) / S; ent -= pp * log(pp + 1e-9); }
            double mean = sum / 64.0, var = 0;
            for (int i = 0; i < 64; ++i) { double dv = qrow[i] - mean; var += dv * dv; }
            var /= 63.0;
            cscore[c] = 0.5 * sqrt(sumsq) + 0.3 * ent + 0.2 * var;
        }
        __syncthreads();
    }

    if (t == 0) {
        bool used[16] = {};
        for (int r = 0; r < 10; ++r) {
            int best = -1;
            for (int c = 0; c < 16; ++c) {
                if (used[c]) continue;
                if (best < 0 || cscore[c] > cscore[best] ||
                    (cscore[c] == cscore[best] && cand[c] < cand[best])) best = c;
            }
            used[best] = true; order[r] = best;
            sel[pair * 10 + r] = cand[best];
        }
    }
    __syncthreads();
    if (t < 64)
        for (int r = 0; r < 10; ++r)
            selq[((size_t)pair * 10 + r) * 64 + t] = cq[order[r]][t];
}

// ---------------- attention partials: online softmax over 1024-row chunks ----------------
__global__ void k_attn_part(const unsigned short* __restrict__ Kb, const unsigned short* __restrict__ Vb,
                            const float* __restrict__ selq, const int* __restrict__ u,
                            float* __restrict__ part)
{
    int bid = blockIdx.x; int pair = bid >> 3; int chunk = bid & 7;
    int b = pair >> 4, h = pair & 15;
    int uu = u[b];
    int t = threadIdx.x;
    __shared__ float qs[64];
    __shared__ float w_sh[1024];
    __shared__ float red[256];
    __shared__ float ored[4][64];
    size_t kvbase = ((size_t)b * 8192 + (size_t)chunk * 1024) * 1024 + h * 64;

    for (int r = 0; r < uu; ++r) {
        if (t < 64) qs[t] = selq[((size_t)pair * 10 + r) * 64 + t] * 0.125f;  // fold 1/sqrt(dk)
        __syncthreads();
        float lg[4]; float lm = -1e30f;
#pragma unroll
        for (int i = 0; i < 4; ++i) {
            int j = t + i * 256;
            const u16x8* kp = (const u16x8*)(Kb + kvbase + (size_t)j * 1024);
            float acc = 0;
#pragma unroll
            for (int d8 = 0; d8 < 8; ++d8) {
                u16x8 kv = kp[d8];
#pragma unroll
                for (int e = 0; e < 8; ++e) acc += qs[d8 * 8 + e] * bf2f(kv[e]);
            }
            lg[i] = acc; lm = fmaxf(lm, acc);
        }
        red[t] = lm; __syncthreads();
        for (int st = 128; st > 0; st >>= 1) { if (t < st) red[t] = fmaxf(red[t], red[t + st]); __syncthreads(); }
        float mc = red[0]; __syncthreads();
        float ls = 0;
#pragma unroll
        for (int i = 0; i < 4; ++i) { float w = expf(lg[i] - mc); w_sh[t + i * 256] = w; ls += w; }
        red[t] = ls; __syncthreads();
        for (int st = 128; st > 0; st >>= 1) { if (t < st) red[t] += red[t + st]; __syncthreads(); }
        float Sc = red[0];
        int g = t >> 6, d = t & 63;
        float o = 0;
        for (int j = g * 256; j < g * 256 + 256; ++j)
            o += w_sh[j] * bf2f(Vb[kvbase + (size_t)j * 1024 + d]);
        ored[g][d] = o; __syncthreads();
        if (t < 64) {
            float oo = ored[0][t] + ored[1][t] + ored[2][t] + ored[3][t];
            float* pp = part + (((size_t)pair * 10 + r) * 8 + chunk) * 66;
            pp[2 + t] = oo;
            if (t == 0) { pp[0] = mc; pp[1] = Sc; }
        }
        __syncthreads();
    }
}

// ---------------- merge chunk partials ----------------
__global__ void k_merge(const float* __restrict__ part, const int* __restrict__ u,
                        float* __restrict__ ao)
{
    int idx = blockIdx.x; int pair = idx / 10; int r = idx % 10; int b = pair >> 4;
    if (r >= u[b]) return;
    int d = threadIdx.x;
    const float* base = part + ((size_t)pair * 10 + r) * 8 * 66;
    float m = -1e30f;
    for (int c = 0; c < 8; ++c) m = fmaxf(m, base[c * 66]);
    float S = 0, o = 0;
    for (int c = 0; c < 8; ++c) {
        float f = expf(base[c * 66] - m);
        S += f * base[c * 66 + 1];
        o += f * base[c * 66 + 2 + d];
    }
    ao[((size_t)pair * 10 + r) * 64 + d] = o / S;
}

// ---------------- output: broadcast bias then sparse scatter ----------------
__global__ void k_bias(const float* __restrict__ bo, float* __restrict__ out) {
    size_t i = (size_t)blockIdx.x * 256 + threadIdx.x;   // 8388608 float4s
    int col4 = (int)(i & 255);
    ((float4*)out)[i] = ((const float4*)bo)[col4];
}

__global__ void k_scatter(const float* __restrict__ ao, const int* __restrict__ sel,
                          const int* __restrict__ u, const float* __restrict__ wo,
                          float* __restrict__ out)
{
    int idx = blockIdx.x; int pair = idx / 10; int r = idx % 10;
    int b = pair >> 4, h = pair & 15;
    if (r >= u[b]) return;
    int t = threadIdx.x;
    __shared__ float a_sh[64];
    if (t < 64) a_sh[t] = ao[((size_t)pair * 10 + r) * 64 + t];
    __syncthreads();
    int l = sel[pair * 10 + r];
    float* orow = out + ((size_t)b * 8192 + l) * 1024;
    for (int j = t; j < 1024; j += 256) {
        const float* wr = wo + (size_t)j * 1024 + h * 64;
        float acc = 0;
#pragma unroll
        for (int d = 0; d < 64; d += 4) {
            float4 w4 = *(const float4*)(wr + d);
            acc += a_sh[d] * w4.x + a_sh[d + 1] * w4.y + a_sh[d + 2] * w4.z + a_sh[d + 3] * w4.w;
        }
        atomicAdd(orow + j, acc);
    }
}

// ---------------- workspace layout ----------------
static constexpr size_t OFF_XB   = 0;                       // 32768*1024*2 = 67108864
static constexpr size_t OFF_WB   = OFF_XB + 67108864;       // 3*1024*1024*2 = 6291456
static constexpr size_t OFF_QB   = OFF_WB + 6291456;        // 67108864
static constexpr size_t OFF_KB   = OFF_QB + 67108864;
static constexpr size_t OFF_VB   = OFF_KB + 67108864;
static constexpr size_t OFF_SC   = OFF_VB + 67108864;       // 524288*4 = 2097152
static constexpr size_t OFF_U    = OFF_SC + 2097152;        // 256
static constexpr size_t OFF_SEL  = OFF_U + 256;             // 4096
static constexpr size_t OFF_SELQ = OFF_SEL + 4096;          // 163840
static constexpr size_t OFF_PART = OFF_SELQ + 163840;       // 64*10*8*66*4 = 1351680
static constexpr size_t OFF_AO   = OFF_PART + 1351680;      // 163840
static constexpr size_t WS_NEED  = OFF_AO + 163840;         // ~266 MiB

extern "C" void kernel_launch(void* const* d_in, const int* in_sizes, int n_in,
                              void* d_out, int out_size, void* d_ws, size_t ws_size,
                              hipStream_t stream)
{
    const float* x  = (const float*)d_in[0];
    const float* wq = (const float*)d_in[1];
    const float* bq = (const float*)d_in[2];
    const float* wk = (const float*)d_in[3];
    const float* bk = (const float*)d_in[4];
    const float* wv = (const float*)d_in[5];
    const float* bv = (const float*)d_in[6];
    const float* wo = (const float*)d_in[7];
    const float* bo = (const float*)d_in[8];
    float* out = (float*)d_out;

    if (ws_size < WS_NEED) return;   // insufficient workspace -> visible failure

    char* ws = (char*)d_ws;
    unsigned short* xb = (unsigned short*)(ws + OFF_XB);
    unsigned short* wb = (unsigned short*)(ws + OFF_WB);
    unsigned short* Qb = (unsigned short*)(ws + OFF_QB);
    unsigned short* Kb = (unsigned short*)(ws + OFF_KB);
    unsigned short* Vb = (unsigned short*)(ws + OFF_VB);
    float* scores = (float*)(ws + OFF_SC);
    int*   u      = (int*)(ws + OFF_U);
    int*   sel    = (int*)(ws + OFF_SEL);
    float* selq   = (float*)(ws + OFF_SELQ);
    float* part   = (float*)(ws + OFF_PART);
    float* ao     = (float*)(ws + OFF_AO);

    k_conv_x   <<<32768, 256, 0, stream>>>(x, xb);
    k_conv_w   <<<3072,  256, 0, stream>>>(wq, wk, wv, wb);
    k_gemm_qkv <<<6144,  256, 0, stream>>>(xb, wb, bq, bk, bv, Qb, Kb, Vb);
    k_score    <<<2048,  256, 0, stream>>>(Qb, scores);
    k_stats    <<<4,     256, 0, stream>>>(scores, u);
    k_topk     <<<64,    256, 0, stream>>>(scores, x, wq, bq, sel, selq);
    k_attn_part<<<512,   256, 0, stream>>>(Kb, Vb, selq, u, part);
    k_merge    <<<640,   64,  0, stream>>>(part, u, ao);
    k_bias     <<<32768, 256, 0, stream>>>(bo, out);
    k_scatter  <<<640,   256, 0, stream>>>(ao, sel, u, wo, out);
}

// Round 2
// 1040.100 us; speedup vs baseline: 1.6553x; 1.6553x over previous
//
#include <hip/hip_runtime.h>
#include <cmath>

// ---------------------------------------------------------------------------
// DynamicProbSparseAttention: B=4, L=8192, D=1024, H=16, dk=64
//   - bf16 MFMA GEMM for Q,K,V (dominant cost, 206 GFLOP)
//   - approx scores from bf16 Q -> top-16 candidate prefilter (k_cand)
//   - exact fp64 rescore of candidates (k_rescore, 1 block per candidate)
//   - top-10 select (k_select)
//   - sparse attention for <=10 rows per (b,h), chunked online softmax
//   - output = broadcast bo + sparse scatter of (attn_out @ wo_head.T)
// ---------------------------------------------------------------------------

typedef short     s16x8 __attribute__((ext_vector_type(8)));
typedef unsigned short u16x8 __attribute__((ext_vector_type(8)));
typedef float     f32x4 __attribute__((ext_vector_type(4)));

__device__ __forceinline__ unsigned short f2bf(float f) {
    unsigned u = __float_as_uint(f);
    u += 0x7fffu + ((u >> 16) & 1u);   // round-to-nearest-even
    return (unsigned short)(u >> 16);
}
__device__ __forceinline__ float bf2f(unsigned short s) {
    return __uint_as_float(((unsigned)s) << 16);
}

__device__ __forceinline__ void async16(const void* g, void* l) {
    __builtin_amdgcn_global_load_lds(
        (const __attribute__((address_space(1))) void*)g,
        (__attribute__((address_space(3))) void*)l, 16, 0, 0);
}

// ---------------- convert kernels ----------------
__global__ void k_conv_x(const float* __restrict__ x, unsigned short* __restrict__ xb) {
    size_t i = (size_t)blockIdx.x * 256 + threadIdx.x;    // 8388608 float4s
    float4 v = ((const float4*)x)[i];
    ushort4 o; o.x = f2bf(v.x); o.y = f2bf(v.y); o.z = f2bf(v.z); o.w = f2bf(v.w);
    ((ushort4*)xb)[i] = o;
}

__global__ void k_conv_w(const float* __restrict__ wq, const float* __restrict__ wk,
                         const float* __restrict__ wv, unsigned short* __restrict__ wb) {
    size_t i = (size_t)blockIdx.x * 256 + threadIdx.x;    // 786432 float4s
    size_t wsel = i >> 18;                                // 262144 float4 per weight
    size_t rem  = i & 262143;
    const float* src = wsel == 0 ? wq : (wsel == 1 ? wk : wv);
    float4 v = ((const float4*)src)[rem];
    ushort4 o; o.x = f2bf(v.x); o.y = f2bf(v.y); o.z = f2bf(v.z); o.w = f2bf(v.w);
    ((ushort4*)wb)[i] = o;
}

// ---------------- fused QKV GEMM (C = x @ W^T + b), bf16 MFMA ----------------
__global__ __launch_bounds__(256) void k_gemm_qkv(
    const unsigned short* __restrict__ xb, const unsigned short* __restrict__ wb,
    const float* __restrict__ bq, const float* __restrict__ bk, const float* __restrict__ bv,
    unsigned short* __restrict__ Qb, unsigned short* __restrict__ Kb, unsigned short* __restrict__ Vb)
{
    __shared__ unsigned short As[128 * 32];
    __shared__ unsigned short Bs[128 * 32];
    int bid = blockIdx.x;
    int mt = bid / 24, rem = bid % 24, wsel = rem >> 3, nt = rem & 7;
    const unsigned short* wbase = wb + ((size_t)wsel << 20) + ((size_t)nt * 128) * 1024;
    const float* bias = wsel == 0 ? bq : (wsel == 1 ? bk : bv);
    unsigned short* outp = wsel == 0 ? Qb : (wsel == 1 ? Kb : Vb);
    int tid = threadIdx.x, wave = tid >> 6, lane = tid & 63;
    int ml = lane & 15, quad = lane >> 4, wm = wave >> 1, wn = wave & 1;
    int lr = lane >> 2, lc = lane & 3;
    const unsigned short* xbase = xb + ((size_t)mt * 128) * 1024;

    f32x4 acc[4][4] = {};
    for (int k0 = 0; k0 < 1024; k0 += 32) {
#pragma unroll
        for (int s = 0; s < 2; ++s) {
            int seg = wave * 2 + s;
            int row = seg * 16 + lr;
            async16(xbase + (size_t)row * 1024 + k0 + lc * 8, &As[seg * 512]);
            async16(wbase + (size_t)row * 1024 + k0 + lc * 8, &Bs[seg * 512]);
        }
        __builtin_amdgcn_s_waitcnt(0);
        __syncthreads();
        s16x8 a[4], b[4];
#pragma unroll
        for (int i = 0; i < 4; ++i) a[i] = *(const s16x8*)&As[(wm * 64 + i * 16 + ml) * 32 + quad * 8];
#pragma unroll
        for (int j = 0; j < 4; ++j) b[j] = *(const s16x8*)&Bs[(wn * 64 + j * 16 + ml) * 32 + quad * 8];
#pragma unroll
        for (int i = 0; i < 4; ++i)
#pragma unroll
            for (int j = 0; j < 4; ++j)
                acc[i][j] = __builtin_amdgcn_mfma_f32_16x16x32_bf16(a[i], b[j], acc[i][j], 0, 0, 0);
        __syncthreads();
    }
#pragma unroll
    for (int i = 0; i < 4; ++i) {
        int grow0 = mt * 128 + wm * 64 + i * 16 + quad * 4;
#pragma unroll
        for (int j = 0; j < 4; ++j) {
            int gcol = nt * 128 + wn * 64 + j * 16 + ml;
            float bvv = bias[gcol];
#pragma unroll
            for (int r = 0; r < 4; ++r)
                outp[(size_t)(grow0 + r) * 1024 + gcol] = f2bf(acc[i][j][r] + bvv);
        }
    }
}

// ---------------- per-(b,h,l) sparsity scores from bf16 Q ----------------
__global__ void k_score(const unsigned short* __restrict__ Qb, float* __restrict__ scores) {
    int gid = blockIdx.x * 256 + threadIdx.x;   // 524288 items
    int r = gid >> 4, h = gid & 15;
    const u16x8* qp = (const u16x8*)(Qb + (size_t)r * 1024 + h * 64);
    float q[64];
#pragma unroll
    for (int i = 0; i < 8; ++i) {
        u16x8 v = qp[i];
#pragma unroll
        for (int e = 0; e < 8; ++e) q[i * 8 + e] = bf2f(v[e]);
    }
    float m = -1e30f;
#pragma unroll
    for (int i = 0; i < 64; ++i) m = fmaxf(m, q[i]);
    float sum = 0.f, sumsq = 0.f, S = 0.f;
#pragma unroll
    for (int i = 0; i < 64; ++i) { sum += q[i]; sumsq += q[i] * q[i]; S += expf(q[i] - m); }
    float ent = 0.f;
#pragma unroll
    for (int i = 0; i < 64; ++i) { float p = expf(q[i] - m) / S; ent -= p * logf(p + 1e-9f); }
    float mean = sum * (1.f / 64.f);
    float var = 0.f;
#pragma unroll
    for (int i = 0; i < 64; ++i) { float d = q[i] - mean; var += d * d; }
    var *= (1.f / 63.f);
    float sc = 0.5f * sqrtf(sumsq) + 0.3f * ent + 0.2f * var;
    int b = r >> 13, l = r & 8191;
    scores[(size_t)((b << 4) + h) * 8192 + l] = sc;
}

// ---------------- u[b] from head-0 score stats ----------------
__global__ void k_stats(const float* __restrict__ scores, int* __restrict__ u) {
    int b = blockIdx.x, t = threadIdx.x;
    const float* s = scores + (size_t)(b * 16) * 8192;    // head 0
    __shared__ double red[256];
    double a0 = 0;
    for (int i = t; i < 8192; i += 256) a0 += (double)s[i];
    red[t] = a0; __syncthreads();
    for (int st = 128; st > 0; st >>= 1) { if (t < st) red[t] += red[t + st]; __syncthreads(); }
    double mean = red[0] / 8192.0;
    __syncthreads();
    double a1 = 0;
    for (int i = t; i < 8192; i += 256) { double d = (double)s[i] - mean; a1 += d * d; }
    red[t] = a1; __syncthreads();
    for (int st = 128; st > 0; st >>= 1) { if (t < st) red[t] += red[t + st]; __syncthreads(); }
    if (t == 0) {
        double sd = sqrt(red[0] / 8191.0);
        double ratio = sd / (mean + 1e-6) * 10.0;
        int f = (int)rint(ratio);
        f = f < 3 ? 3 : (f > 10 ? 10 : f);
        u[b] = f;
    }
}

// ---------------- top-16 candidate selection (parallel argmax x16) ----------------
__global__ __launch_bounds__(1024) void k_cand(const float* __restrict__ scores,
                                               int* __restrict__ cand)
{
    int pair = blockIdx.x; int t = threadIdx.x;
    __shared__ float s_lds[8192];
    __shared__ float wvv[16];
    __shared__ int   wii[16];
    const float* sp = scores + (size_t)pair * 8192;
    for (int i = t; i < 8192; i += 1024) s_lds[i] = sp[i];
    __syncthreads();
    for (int it = 0; it < 16; ++it) {
        float bv = -1e30f; int bi = 0x7fffffff;
#pragma unroll
        for (int k = 0; k < 8; ++k) {
            int i = t + k * 1024;
            float v = s_lds[i];
            if (v > bv || (v == bv && i < bi)) { bv = v; bi = i; }
        }
#pragma unroll
        for (int off = 32; off > 0; off >>= 1) {
            float ov = __shfl_down(bv, off);
            int   oi = __shfl_down(bi, off);
            if (ov > bv || (ov == bv && oi < bi)) { bv = ov; bi = oi; }
        }
        if ((t & 63) == 0) { wvv[t >> 6] = bv; wii[t >> 6] = bi; }
        __syncthreads();
        if (t == 0) {
            float fv = wvv[0]; int fi = wii[0];
            for (int k = 1; k < 16; ++k)
                if (wvv[k] > fv || (wvv[k] == fv && wii[k] < fi)) { fv = wvv[k]; fi = wii[k]; }
            cand[pair * 16 + it] = fi;
            s_lds[fi] = -1e30f;
        }
        __syncthreads();
    }
}

// ---------------- exact fp64 rescore, one block per (pair,candidate) ----------------
__global__ __launch_bounds__(256) void k_rescore(
    const int* __restrict__ cand, const float* __restrict__ x,
    const float* __restrict__ wq, const float* __restrict__ bq,
    double* __restrict__ cscore, float* __restrict__ cq)
{
    int bid = blockIdx.x;             // pair*16 + c
    int pair = bid >> 4, c = bid & 15;
    int b = pair >> 4, h = pair & 15;
    int t = threadIdx.x;
    __shared__ float  xrow[1024];
    __shared__ double dred[256];
    __shared__ double qrow[64];

    int l = cand[bid];
    const float* xr = x + ((size_t)b * 8192 + l) * 1024;
    for (int i = t; i < 1024; i += 256) xrow[i] = xr[i];
    __syncthreads();

    int d = t >> 2, ks = t & 3;
    const float* wr = wq + (size_t)(h * 64 + d) * 1024 + ks * 256;
    const float* xs = xrow + ks * 256;
    double p = 0;
    for (int k = 0; k < 256; k += 4) {
        float4 w4 = *(const float4*)(wr + k);
        float4 x4 = *(const float4*)(xs + k);
        p += (double)w4.x * x4.x + (double)w4.y * x4.y +
             (double)w4.z * x4.z + (double)w4.w * x4.w;
    }
    dred[t] = p; __syncthreads();
    if ((t & 3) == 0)
        qrow[t >> 2] = dred[t] + dred[t + 1] + dred[t + 2] + dred[t + 3] + (double)bq[h * 64 + (t >> 2)];
    __syncthreads();

    if (t < 64) {
        double q = qrow[t];
        cq[(size_t)bid * 64 + t] = (float)q;
        // parallel score on wave 0: max, sums, entropy via shuffle reduce
        double m = q;
#pragma unroll
        for (int off = 32; off > 0; off >>= 1) m = fmax(m, __shfl_down(m, off));
        m = __shfl(m, 0);
        double e = exp(q - m);
        double sum = q, sumsq = q * q, S = e;
#pragma unroll
        for (int off = 32; off > 0; off >>= 1) {
            sum += __shfl_down(sum, off);
            sumsq += __shfl_down(sumsq, off);
            S += __shfl_down(S, off);
        }
        sum = __shfl(sum, 0); sumsq = __shfl(sumsq, 0); S = __shfl(S, 0);
        double pp = e / S;
        double entc = -pp * log(pp + 1e-9);
        double mean = sum / 64.0;
        double dv = q - mean;
        double varc = dv * dv;
#pragma unroll
        for (int off = 32; off > 0; off >>= 1) {
            entc += __shfl_down(entc, off);
            varc += __shfl_down(varc, off);
        }
        if (t == 0)
            cscore[bid] = 0.5 * sqrt(sumsq) + 0.3 * entc + 0.2 * (varc / 63.0);
    }
}

// ---------------- top-10-of-16 select ----------------
__global__ void k_select(const int* __restrict__ cand, const double* __restrict__ cscore,
                         const float* __restrict__ cq,
                         int* __restrict__ sel, float* __restrict__ selq)
{
    int pair = blockIdx.x; int t = threadIdx.x;   // 64 threads
    __shared__ int order[10];
    if (t == 0) {
        bool used[16] = {};
        for (int r = 0; r < 10; ++r) {
            int best = -1;
            for (int c = 0; c < 16; ++c) {
                if (used[c]) continue;
                int ic = pair * 16 + c;
                if (best < 0 || cscore[ic] > cscore[pair * 16 + best] ||
                    (cscore[ic] == cscore[pair * 16 + best] && cand[ic] < cand[pair * 16 + best]))
                    best = c;
            }
            used[best] = true; order[r] = best;
            sel[pair * 10 + r] = cand[pair * 16 + best];
        }
    }
    __syncthreads();
    for (int r = 0; r < 10; ++r)
        selq[((size_t)pair * 10 + r) * 64 + t] = cq[((size_t)pair * 16 + order[r]) * 64 + t];
}

// ---------------- attention partials: online softmax over 1024-row chunks ----------------
__global__ void k_attn_part(const unsigned short* __restrict__ Kb, const unsigned short* __restrict__ Vb,
                            const float* __restrict__ selq, const int* __restrict__ u,
                            float* __restrict__ part)
{
    int bid = blockIdx.x; int pair = bid >> 3; int chunk = bid & 7;
    int b = pair >> 4, h = pair & 15;
    int uu = u[b];
    int t = threadIdx.x;
    __shared__ float qs[64];
    __shared__ float w_sh[1024];
    __shared__ float red[256];
    __shared__ float ored[4][64];
    size_t kvbase = ((size_t)b * 8192 + (size_t)chunk * 1024) * 1024 + h * 64;

    for (int r = 0; r < uu; ++r) {
        if (t < 64) qs[t] = selq[((size_t)pair * 10 + r) * 64 + t] * 0.125f;
        __syncthreads();
        float lg[4]; float lm = -1e30f;
#pragma unroll
        for (int i = 0; i < 4; ++i) {
            int j = t + i * 256;
            const u16x8* kp = (const u16x8*)(Kb + kvbase + (size_t)j * 1024);
            float acc = 0;
#pragma unroll
            for (int d8 = 0; d8 < 8; ++d8) {
                u16x8 kv = kp[d8];
#pragma unroll
                for (int e = 0; e < 8; ++e) acc += qs[d8 * 8 + e] * bf2f(kv[e]);
            }
            lg[i] = acc; lm = fmaxf(lm, acc);
        }
        red[t] = lm; __syncthreads();
        for (int st = 128; st > 0; st >>= 1) { if (t < st) red[t] = fmaxf(red[t], red[t + st]); __syncthreads(); }
        float mc = red[0]; __syncthreads();
        float ls = 0;
#pragma unroll
        for (int i = 0; i < 4; ++i) { float w = expf(lg[i] - mc); w_sh[t + i * 256] = w; ls += w; }
        red[t] = ls; __syncthreads();
        for (int st = 128; st > 0; st >>= 1) { if (t < st) red[t] += red[t + st]; __syncthreads(); }
        float Sc = red[0];
        int g = t >> 6, d = t & 63;
        float o = 0;
        for (int j = g * 256; j < g * 256 + 256; ++j)
            o += w_sh[j] * bf2f(Vb[kvbase + (size_t)j * 1024 + d]);
        ored[g][d] = o; __syncthreads();
        if (t < 64) {
            float oo = ored[0][t] + ored[1][t] + ored[2][t] + ored[3][t];
            float* pp = part + (((size_t)pair * 10 + r) * 8 + chunk) * 66;
            pp[2 + t] = oo;
            if (t == 0) { pp[0] = mc; pp[1] = Sc; }
        }
        __syncthreads();
    }
}

// ---------------- merge chunk partials ----------------
__global__ void k_merge(const float* __restrict__ part, const int* __restrict__ u,
                        float* __restrict__ ao)
{
    int idx = blockIdx.x; int pair = idx / 10; int r = idx % 10; int b = pair >> 4;
    if (r >= u[b]) return;
    int d = threadIdx.x;
    const float* base = part + ((size_t)pair * 10 + r) * 8 * 66;
    float m = -1e30f;
    for (int c = 0; c < 8; ++c) m = fmaxf(m, base[c * 66]);
    float S = 0, o = 0;
    for (int c = 0; c < 8; ++c) {
        float f = expf(base[c * 66] - m);
        S += f * base[c * 66 + 1];
        o += f * base[c * 66 + 2 + d];
    }
    ao[((size_t)pair * 10 + r) * 64 + d] = o / S;
}

// ---------------- output: broadcast bias then sparse scatter ----------------
__global__ void k_bias(const float* __restrict__ bo, float* __restrict__ out) {
    size_t i = (size_t)blockIdx.x * 256 + threadIdx.x;   // 8388608 float4s
    int col4 = (int)(i & 255);
    ((float4*)out)[i] = ((const float4*)bo)[col4];
}

__global__ void k_scatter(const float* __restrict__ ao, const int* __restrict__ sel,
                          const int* __restrict__ u, const float* __restrict__ wo,
                          float* __restrict__ out)
{
    int idx = blockIdx.x; int pair = idx / 10; int r = idx % 10;
    int b = pair >> 4, h = pair & 15;
    if (r >= u[b]) return;
    int t = threadIdx.x;
    __shared__ float a_sh[64];
    if (t < 64) a_sh[t] = ao[((size_t)pair * 10 + r) * 64 + t];
    __syncthreads();
    int l = sel[pair * 10 + r];
    float* orow = out + ((size_t)b * 8192 + l) * 1024;
    for (int j = t; j < 1024; j += 256) {
        const float* wr = wo + (size_t)j * 1024 + h * 64;
        float acc = 0;
#pragma unroll
        for (int d = 0; d < 64; d += 4) {
            float4 w4 = *(const float4*)(wr + d);
            acc += a_sh[d] * w4.x + a_sh[d + 1] * w4.y + a_sh[d + 2] * w4.z + a_sh[d + 3] * w4.w;
        }
        atomicAdd(orow + j, acc);
    }
}

// ---------------- workspace layout ----------------
static constexpr size_t OFF_XB    = 0;                        // 67108864
static constexpr size_t OFF_WB    = OFF_XB + 67108864;        // 6291456
static constexpr size_t OFF_QB    = OFF_WB + 6291456;         // 67108864
static constexpr size_t OFF_KB    = OFF_QB + 67108864;
static constexpr size_t OFF_VB    = OFF_KB + 67108864;
static constexpr size_t OFF_SC    = OFF_VB + 67108864;        // 2097152
static constexpr size_t OFF_U     = OFF_SC + 2097152;         // 256
static constexpr size_t OFF_SEL   = OFF_U + 256;              // 4096
static constexpr size_t OFF_SELQ  = OFF_SEL + 4096;           // 163840
static constexpr size_t OFF_PART  = OFF_SELQ + 163840;        // 1351680
static constexpr size_t OFF_AO    = OFF_PART + 1351680;       // 163840
static constexpr size_t OFF_CAND  = OFF_AO + 163840;          // 64*16*4 = 4096
static constexpr size_t OFF_CSC   = OFF_CAND + 4096;          // 64*16*8 = 8192
static constexpr size_t OFF_CQ    = OFF_CSC + 8192;           // 64*16*64*4 = 262144
static constexpr size_t WS_NEED   = OFF_CQ + 262144;

extern "C" void kernel_launch(void* const* d_in, const int* in_sizes, int n_in,
                              void* d_out, int out_size, void* d_ws, size_t ws_size,
                              hipStream_t stream)
{
    const float* x  = (const float*)d_in[0];
    const float* wq = (const float*)d_in[1];
    const float* bq = (const float*)d_in[2];
    const float* wk = (const float*)d_in[3];
    const float* bk = (const float*)d_in[4];
    const float* wv = (const float*)d_in[5];
    const float* bv = (const float*)d_in[6];
    const float* wo = (const float*)d_in[7];
    const float* bo = (const float*)d_in[8];
    float* out = (float*)d_out;

    if (ws_size < WS_NEED) return;

    char* ws = (char*)d_ws;
    unsigned short* xb = (unsigned short*)(ws + OFF_XB);
    unsigned short* wb = (unsigned short*)(ws + OFF_WB);
    unsigned short* Qb = (unsigned short*)(ws + OFF_QB);
    unsigned short* Kb = (unsigned short*)(ws + OFF_KB);
    unsigned short* Vb = (unsigned short*)(ws + OFF_VB);
    float*  scores = (float*)(ws + OFF_SC);
    int*    u      = (int*)(ws + OFF_U);
    int*    sel    = (int*)(ws + OFF_SEL);
    float*  selq   = (float*)(ws + OFF_SELQ);
    float*  part   = (float*)(ws + OFF_PART);
    float*  ao     = (float*)(ws + OFF_AO);
    int*    cand   = (int*)(ws + OFF_CAND);
    double* cscore = (double*)(ws + OFF_CSC);
    float*  cq     = (float*)(ws + OFF_CQ);

    k_conv_x   <<<32768, 256,  0, stream>>>(x, xb);
    k_conv_w   <<<3072,  256,  0, stream>>>(wq, wk, wv, wb);
    k_gemm_qkv <<<6144,  256,  0, stream>>>(xb, wb, bq, bk, bv, Qb, Kb, Vb);
    k_score    <<<2048,  256,  0, stream>>>(Qb, scores);
    k_stats    <<<4,     256,  0, stream>>>(scores, u);
    k_cand     <<<64,    1024, 0, stream>>>(scores, cand);
    k_rescore  <<<1024,  256,  0, stream>>>(cand, x, wq, bq, cscore, cq);
    k_select   <<<64,    64,   0, stream>>>(cand, cscore, cq, sel, selq);
    k_attn_part<<<512,   256,  0, stream>>>(Kb, Vb, selq, u, part);
    k_merge    <<<640,   64,   0, stream>>>(part, u, ao);
    k_bias     <<<32768, 256,  0, stream>>>(bo, out);
    k_scatter  <<<640,   256,  0, stream>>>(ao, sel, u, wo, out);
}

// Round 3
// 756.806 us; speedup vs baseline: 2.2749x; 1.3743x over previous
//
#include <hip/hip_runtime.h>
#include <cmath>

// ---------------------------------------------------------------------------
// DynamicProbSparseAttention: B=4, L=8192, D=1024, H=16, dk=64
//   - bf16 MFMA GEMM for Q,K,V (dominant cost, 206 GFLOP)
//   - approx scores from bf16 Q -> top-16 candidate prefilter (k_cand)
//   - exact fp64 rescore of candidates (k_rescore, 1 block per candidate)
//   - top-10 select (k_select)
//   - sparse attention: single-pass K/V, 2048 blocks, all u rows at once
//   - output = broadcast bo + sparse scatter of (attn_out @ wo_head.T)
// ---------------------------------------------------------------------------

typedef short     s16x8 __attribute__((ext_vector_type(8)));
typedef unsigned short u16x8 __attribute__((ext_vector_type(8)));
typedef unsigned short u16x4 __attribute__((ext_vector_type(4)));
typedef float     f32x4 __attribute__((ext_vector_type(4)));

__device__ __forceinline__ unsigned short f2bf(float f) {
    unsigned u = __float_as_uint(f);
    u += 0x7fffu + ((u >> 16) & 1u);   // round-to-nearest-even
    return (unsigned short)(u >> 16);
}
__device__ __forceinline__ float bf2f(unsigned short s) {
    return __uint_as_float(((unsigned)s) << 16);
}

__device__ __forceinline__ void async16(const void* g, void* l) {
    __builtin_amdgcn_global_load_lds(
        (const __attribute__((address_space(1))) void*)g,
        (__attribute__((address_space(3))) void*)l, 16, 0, 0);
}

// ---------------- convert kernels ----------------
__global__ void k_conv_x(const float* __restrict__ x, unsigned short* __restrict__ xb) {
    size_t i = (size_t)blockIdx.x * 256 + threadIdx.x;    // 8388608 float4s
    float4 v = ((const float4*)x)[i];
    ushort4 o; o.x = f2bf(v.x); o.y = f2bf(v.y); o.z = f2bf(v.z); o.w = f2bf(v.w);
    ((ushort4*)xb)[i] = o;
}

__global__ void k_conv_w(const float* __restrict__ wq, const float* __restrict__ wk,
                         const float* __restrict__ wv, unsigned short* __restrict__ wb) {
    size_t i = (size_t)blockIdx.x * 256 + threadIdx.x;    // 786432 float4s
    size_t wsel = i >> 18;                                // 262144 float4 per weight
    size_t rem  = i & 262143;
    const float* src = wsel == 0 ? wq : (wsel == 1 ? wk : wv);
    float4 v = ((const float4*)src)[rem];
    ushort4 o; o.x = f2bf(v.x); o.y = f2bf(v.y); o.z = f2bf(v.z); o.w = f2bf(v.w);
    ((ushort4*)wb)[i] = o;
}

// ---------------- fused QKV GEMM (C = x @ W^T + b), bf16 MFMA ----------------
__global__ __launch_bounds__(256) void k_gemm_qkv(
    const unsigned short* __restrict__ xb, const unsigned short* __restrict__ wb,
    const float* __restrict__ bq, const float* __restrict__ bk, const float* __restrict__ bv,
    unsigned short* __restrict__ Qb, unsigned short* __restrict__ Kb, unsigned short* __restrict__ Vb)
{
    __shared__ unsigned short As[128 * 32];
    __shared__ unsigned short Bs[128 * 32];
    int bid = blockIdx.x;
    int mt = bid / 24, rem = bid % 24, wsel = rem >> 3, nt = rem & 7;
    const unsigned short* wbase = wb + ((size_t)wsel << 20) + ((size_t)nt * 128) * 1024;
    const float* bias = wsel == 0 ? bq : (wsel == 1 ? bk : bv);
    unsigned short* outp = wsel == 0 ? Qb : (wsel == 1 ? Kb : Vb);
    int tid = threadIdx.x, wave = tid >> 6, lane = tid & 63;
    int ml = lane & 15, quad = lane >> 4, wm = wave >> 1, wn = wave & 1;
    int lr = lane >> 2, lc = lane & 3;
    const unsigned short* xbase = xb + ((size_t)mt * 128) * 1024;

    f32x4 acc[4][4] = {};
    for (int k0 = 0; k0 < 1024; k0 += 32) {
#pragma unroll
        for (int s = 0; s < 2; ++s) {
            int seg = wave * 2 + s;
            int row = seg * 16 + lr;
            async16(xbase + (size_t)row * 1024 + k0 + lc * 8, &As[seg * 512]);
            async16(wbase + (size_t)row * 1024 + k0 + lc * 8, &Bs[seg * 512]);
        }
        __builtin_amdgcn_s_waitcnt(0);
        __syncthreads();
        s16x8 a[4], b[4];
#pragma unroll
        for (int i = 0; i < 4; ++i) a[i] = *(const s16x8*)&As[(wm * 64 + i * 16 + ml) * 32 + quad * 8];
#pragma unroll
        for (int j = 0; j < 4; ++j) b[j] = *(const s16x8*)&Bs[(wn * 64 + j * 16 + ml) * 32 + quad * 8];
#pragma unroll
        for (int i = 0; i < 4; ++i)
#pragma unroll
            for (int j = 0; j < 4; ++j)
                acc[i][j] = __builtin_amdgcn_mfma_f32_16x16x32_bf16(a[i], b[j], acc[i][j], 0, 0, 0);
        __syncthreads();
    }
#pragma unroll
    for (int i = 0; i < 4; ++i) {
        int grow0 = mt * 128 + wm * 64 + i * 16 + quad * 4;
#pragma unroll
        for (int j = 0; j < 4; ++j) {
            int gcol = nt * 128 + wn * 64 + j * 16 + ml;
            float bvv = bias[gcol];
#pragma unroll
            for (int r = 0; r < 4; ++r)
                outp[(size_t)(grow0 + r) * 1024 + gcol] = f2bf(acc[i][j][r] + bvv);
        }
    }
}

// ---------------- per-(b,h,l) sparsity scores from bf16 Q ----------------
__global__ void k_score(const unsigned short* __restrict__ Qb, float* __restrict__ scores) {
    int gid = blockIdx.x * 256 + threadIdx.x;   // 524288 items
    int r = gid >> 4, h = gid & 15;
    const u16x8* qp = (const u16x8*)(Qb + (size_t)r * 1024 + h * 64);
    float q[64];
#pragma unroll
    for (int i = 0; i < 8; ++i) {
        u16x8 v = qp[i];
#pragma unroll
        for (int e = 0; e < 8; ++e) q[i * 8 + e] = bf2f(v[e]);
    }
    float m = -1e30f;
#pragma unroll
    for (int i = 0; i < 64; ++i) m = fmaxf(m, q[i]);
    float sum = 0.f, sumsq = 0.f, S = 0.f;
#pragma unroll
    for (int i = 0; i < 64; ++i) { sum += q[i]; sumsq += q[i] * q[i]; S += expf(q[i] - m); }
    float ent = 0.f;
#pragma unroll
    for (int i = 0; i < 64; ++i) { float p = expf(q[i] - m) / S; ent -= p * logf(p + 1e-9f); }
    float mean = sum * (1.f / 64.f);
    float var = 0.f;
#pragma unroll
    for (int i = 0; i < 64; ++i) { float d = q[i] - mean; var += d * d; }
    var *= (1.f / 63.f);
    float sc = 0.5f * sqrtf(sumsq) + 0.3f * ent + 0.2f * var;
    int b = r >> 13, l = r & 8191;
    scores[(size_t)((b << 4) + h) * 8192 + l] = sc;
}

// ---------------- u[b] from head-0 score stats ----------------
__global__ void k_stats(const float* __restrict__ scores, int* __restrict__ u) {
    int b = blockIdx.x, t = threadIdx.x;
    const float* s = scores + (size_t)(b * 16) * 8192;    // head 0
    __shared__ double red[256];
    double a0 = 0;
    for (int i = t; i < 8192; i += 256) a0 += (double)s[i];
    red[t] = a0; __syncthreads();
    for (int st = 128; st > 0; st >>= 1) { if (t < st) red[t] += red[t + st]; __syncthreads(); }
    double mean = red[0] / 8192.0;
    __syncthreads();
    double a1 = 0;
    for (int i = t; i < 8192; i += 256) { double d = (double)s[i] - mean; a1 += d * d; }
    red[t] = a1; __syncthreads();
    for (int st = 128; st > 0; st >>= 1) { if (t < st) red[t] += red[t + st]; __syncthreads(); }
    if (t == 0) {
        double sd = sqrt(red[0] / 8191.0);
        double ratio = sd / (mean + 1e-6) * 10.0;
        int f = (int)rint(ratio);
        f = f < 3 ? 3 : (f > 10 ? 10 : f);
        u[b] = f;
    }
}

// ---------------- top-16 candidate selection (parallel argmax x16) ----------------
__global__ __launch_bounds__(1024) void k_cand(const float* __restrict__ scores,
                                               int* __restrict__ cand)
{
    int pair = blockIdx.x; int t = threadIdx.x;
    __shared__ float s_lds[8192];
    __shared__ float wvv[16];
    __shared__ int   wii[16];
    const float* sp = scores + (size_t)pair * 8192;
    for (int i = t; i < 8192; i += 1024) s_lds[i] = sp[i];
    __syncthreads();
    for (int it = 0; it < 16; ++it) {
        float bv = -1e30f; int bi = 0x7fffffff;
#pragma unroll
        for (int k = 0; k < 8; ++k) {
            int i = t + k * 1024;
            float v = s_lds[i];
            if (v > bv || (v == bv && i < bi)) { bv = v; bi = i; }
        }
#pragma unroll
        for (int off = 32; off > 0; off >>= 1) {
            float ov = __shfl_down(bv, off);
            int   oi = __shfl_down(bi, off);
            if (ov > bv || (ov == bv && oi < bi)) { bv = ov; bi = oi; }
        }
        if ((t & 63) == 0) { wvv[t >> 6] = bv; wii[t >> 6] = bi; }
        __syncthreads();
        if (t == 0) {
            float fv = wvv[0]; int fi = wii[0];
            for (int k = 1; k < 16; ++k)
                if (wvv[k] > fv || (wvv[k] == fv && wii[k] < fi)) { fv = wvv[k]; fi = wii[k]; }
            cand[pair * 16 + it] = fi;
            s_lds[fi] = -1e30f;
        }
        __syncthreads();
    }
}

// ---------------- exact fp64 rescore, one block per (pair,candidate) ----------------
__global__ __launch_bounds__(256) void k_rescore(
    const int* __restrict__ cand, const float* __restrict__ x,
    const float* __restrict__ wq, const float* __restrict__ bq,
    double* __restrict__ cscore, float* __restrict__ cq)
{
    int bid = blockIdx.x;             // pair*16 + c
    int pair = bid >> 4;
    int b = pair >> 4, h = pair & 15;
    int t = threadIdx.x;
    __shared__ float  xrow[1024];
    __shared__ double dred[256];
    __shared__ double qrow[64];

    int l = cand[bid];
    const float* xr = x + ((size_t)b * 8192 + l) * 1024;
    for (int i = t; i < 1024; i += 256) xrow[i] = xr[i];
    __syncthreads();

    int d = t >> 2, ks = t & 3;
    const float* wr = wq + (size_t)(h * 64 + d) * 1024 + ks * 256;
    const float* xs = xrow + ks * 256;
    double p = 0;
    for (int k = 0; k < 256; k += 4) {
        float4 w4 = *(const float4*)(wr + k);
        float4 x4 = *(const float4*)(xs + k);
        p += (double)w4.x * x4.x + (double)w4.y * x4.y +
             (double)w4.z * x4.z + (double)w4.w * x4.w;
    }
    dred[t] = p; __syncthreads();
    if ((t & 3) == 0)
        qrow[t >> 2] = dred[t] + dred[t + 1] + dred[t + 2] + dred[t + 3] + (double)bq[h * 64 + (t >> 2)];
    __syncthreads();

    if (t < 64) {
        double q = qrow[t];
        cq[(size_t)bid * 64 + t] = (float)q;
        double m = q;
#pragma unroll
        for (int off = 32; off > 0; off >>= 1) m = fmax(m, __shfl_down(m, off));
        m = __shfl(m, 0);
        double e = exp(q - m);
        double sum = q, sumsq = q * q, S = e;
#pragma unroll
        for (int off = 32; off > 0; off >>= 1) {
            sum += __shfl_down(sum, off);
            sumsq += __shfl_down(sumsq, off);
            S += __shfl_down(S, off);
        }
        sum = __shfl(sum, 0); sumsq = __shfl(sumsq, 0); S = __shfl(S, 0);
        double pp = e / S;
        double entc = -pp * log(pp + 1e-9);
        double mean = sum / 64.0;
        double dv = q - mean;
        double varc = dv * dv;
#pragma unroll
        for (int off = 32; off > 0; off >>= 1) {
            entc += __shfl_down(entc, off);
            varc += __shfl_down(varc, off);
        }
        if (t == 0)
            cscore[bid] = 0.5 * sqrt(sumsq) + 0.3 * entc + 0.2 * (varc / 63.0);
    }
}

// ---------------- top-10-of-16 select ----------------
__global__ void k_select(const int* __restrict__ cand, const double* __restrict__ cscore,
                         const float* __restrict__ cq,
                         int* __restrict__ sel, float* __restrict__ selq)
{
    int pair = blockIdx.x; int t = threadIdx.x;   // 64 threads
    __shared__ int order[10];
    if (t == 0) {
        bool used[16] = {};
        for (int r = 0; r < 10; ++r) {
            int best = -1;
            for (int c = 0; c < 16; ++c) {
                if (used[c]) continue;
                int ic = pair * 16 + c;
                if (best < 0 || cscore[ic] > cscore[pair * 16 + best] ||
                    (cscore[ic] == cscore[pair * 16 + best] && cand[ic] < cand[pair * 16 + best]))
                    best = c;
            }
            used[best] = true; order[r] = best;
            sel[pair * 10 + r] = cand[pair * 16 + best];
        }
    }
    __syncthreads();
    for (int r = 0; r < 10; ++r)
        selq[((size_t)pair * 10 + r) * 64 + t] = cq[((size_t)pair * 16 + order[r]) * 64 + t];
}

// ---------------- attention partials: one K/V pass, 256-row chunks ----------------
// grid: 64 pairs x 32 chunks; 256 threads. part entries are 64 half-chunks
// of 128 rows each: [pair][r][hc<64]{m, S, o[64]}.
__global__ __launch_bounds__(256) void k_attn_part(
    const unsigned short* __restrict__ Kb, const unsigned short* __restrict__ Vb,
    const float* __restrict__ selq, const int* __restrict__ u,
    float* __restrict__ part)
{
    int bid = blockIdx.x;
    int pair = bid >> 5, chunk = bid & 31;
    int b = pair >> 4, h = pair & 15;
    int uu = u[b];
    int t = threadIdx.x, wave = t >> 6, lane = t & 63;

    __shared__ float q_sh[10][64];
    __shared__ float w_sh[10][256];
    __shared__ unsigned short V_sh[256][68];   // pad 64->68 (34 words, conflict-light)
    __shared__ float mc_sh[10][2], Sc_sh[10][2];

    size_t kvbase = ((size_t)b * 8192 + (size_t)chunk * 256) * 1024 + h * 64;

    // stage q (scaled by 1/sqrt(dk)); issue K/V row loads (16B/lane)
    for (int i = t; i < uu * 64; i += 256)
        q_sh[i >> 6][i & 63] = selq[(size_t)pair * 640 + i] * 0.125f;

    const u16x8* kr = (const u16x8*)(Kb + kvbase + (size_t)t * 1024);
    const u16x8* vr = (const u16x8*)(Vb + kvbase + (size_t)t * 1024);
    u16x8 vreg[8];
#pragma unroll
    for (int k8 = 0; k8 < 8; ++k8) vreg[k8] = vr[k8];
#pragma unroll
    for (int k8 = 0; k8 < 8; ++k8) {
        *(u16x4*)&V_sh[t][k8 * 8]     = { vreg[k8][0], vreg[k8][1], vreg[k8][2], vreg[k8][3] };
        *(u16x4*)&V_sh[t][k8 * 8 + 4] = { vreg[k8][4], vreg[k8][5], vreg[k8][6], vreg[k8][7] };
    }
    float krow[64];
#pragma unroll
    for (int k8 = 0; k8 < 8; ++k8) {
        u16x8 kv = kr[k8];
#pragma unroll
        for (int e = 0; e < 8; ++e) krow[k8 * 8 + e] = bf2f(kv[e]);
    }
    __syncthreads();   // q_sh ready (V_sh consumed only after next barrier)

    // QK: thread t owns row t; logits for all uu rows
    for (int rr = 0; rr < uu; ++rr) {
        const float4* qp = (const float4*)q_sh[rr];
        float acc = 0.f;
#pragma unroll
        for (int i4 = 0; i4 < 16; ++i4) {
            float4 q4 = qp[i4];
            acc += q4.x * krow[i4 * 4] + q4.y * krow[i4 * 4 + 1] +
                   q4.z * krow[i4 * 4 + 2] + q4.w * krow[i4 * 4 + 3];
        }
        w_sh[rr][t] = acc;
    }
    __syncthreads();

    // per-half-chunk softmax: wave handles rr = wave, wave+4, wave+8
    for (int rr = wave; rr < uu; rr += 4) {
        float4 wv = *(const float4*)&w_sh[rr][lane * 4];
        float m4 = fmaxf(fmaxf(wv.x, wv.y), fmaxf(wv.z, wv.w));
#pragma unroll
        for (int off = 16; off > 0; off >>= 1) m4 = fmaxf(m4, __shfl_xor(m4, off));
        float e0 = expf(wv.x - m4), e1 = expf(wv.y - m4);
        float e2 = expf(wv.z - m4), e3 = expf(wv.w - m4);
        float s = e0 + e1 + e2 + e3;
#pragma unroll
        for (int off = 16; off > 0; off >>= 1) s += __shfl_xor(s, off);
        float4 ev = { e0, e1, e2, e3 };
        *(float4*)&w_sh[rr][lane * 4] = ev;
        if ((lane & 31) == 0) { int jh = lane >> 5; mc_sh[rr][jh] = m4; Sc_sh[rr][jh] = s; }
    }
    __syncthreads();

    // V accumulate: thread (jh, rr0, dp); each handles 128 j for d-pair dp
    int jh = t >> 7, tt = t & 127, dp = tt & 31;
    for (int rr = tt >> 5; rr < uu; rr += 4) {
        float o0 = 0.f, o1 = 0.f;
        int j0 = jh * 128;
        for (int j = j0; j < j0 + 128; j += 4) {
            float4 w4 = *(const float4*)&w_sh[rr][j];
#pragma unroll
            for (int jj = 0; jj < 4; ++jj) {
                unsigned v = *(const unsigned*)&V_sh[j + jj][dp * 2];
                float w1 = jj == 0 ? w4.x : (jj == 1 ? w4.y : (jj == 2 ? w4.z : w4.w));
                o0 += w1 * __uint_as_float(v << 16);
                o1 += w1 * __uint_as_float(v & 0xffff0000u);
            }
        }
        float* pp = part + (((size_t)pair * 10 + rr) * 64 + chunk * 2 + jh) * 66;
        float2 o2 = { o0, o1 };
        *(float2*)&pp[2 + dp * 2] = o2;
        if (dp == 0) { pp[0] = mc_sh[rr][jh]; pp[1] = Sc_sh[rr][jh]; }
    }
}

// ---------------- merge half-chunk partials ----------------
__global__ void k_merge(const float* __restrict__ part, const int* __restrict__ u,
                        float* __restrict__ ao)
{
    int idx = blockIdx.x; int pair = idx / 10; int r = idx % 10; int b = pair >> 4;
    if (r >= u[b]) return;
    int d = threadIdx.x;
    const float* base = part + ((size_t)pair * 10 + r) * 64 * 66;
    float m = -1e30f;
    for (int c = 0; c < 64; ++c) m = fmaxf(m, base[c * 66]);
    float S = 0, o = 0;
    for (int c = 0; c < 64; ++c) {
        float f = expf(base[c * 66] - m);
        S += f * base[c * 66 + 1];
        o += f * base[c * 66 + 2 + d];
    }
    ao[((size_t)pair * 10 + r) * 64 + d] = o / S;
}

// ---------------- output: broadcast bias then sparse scatter ----------------
__global__ void k_bias(const float* __restrict__ bo, float* __restrict__ out) {
    size_t i = (size_t)blockIdx.x * 256 + threadIdx.x;   // 8388608 float4s
    int col4 = (int)(i & 255);
    ((float4*)out)[i] = ((const float4*)bo)[col4];
}

__global__ void k_scatter(const float* __restrict__ ao, const int* __restrict__ sel,
                          const int* __restrict__ u, const float* __restrict__ wo,
                          float* __restrict__ out)
{
    int idx = blockIdx.x; int pair = idx / 10; int r = idx % 10;
    int b = pair >> 4, h = pair & 15;
    if (r >= u[b]) return;
    int t = threadIdx.x;
    __shared__ float a_sh[64];
    if (t < 64) a_sh[t] = ao[((size_t)pair * 10 + r) * 64 + t];
    __syncthreads();
    int l = sel[pair * 10 + r];
    float* orow = out + ((size_t)b * 8192 + l) * 1024;
    for (int j = t; j < 1024; j += 256) {
        const float* wr = wo + (size_t)j * 1024 + h * 64;
        float acc = 0;
#pragma unroll
        for (int d = 0; d < 64; d += 4) {
            float4 w4 = *(const float4*)(wr + d);
            acc += a_sh[d] * w4.x + a_sh[d + 1] * w4.y + a_sh[d + 2] * w4.z + a_sh[d + 3] * w4.w;
        }
        atomicAdd(orow + j, acc);
    }
}

// ---------------- workspace layout ----------------
static constexpr size_t OFF_XB    = 0;                        // 67108864
static constexpr size_t OFF_WB    = OFF_XB + 67108864;        // 6291456
static constexpr size_t OFF_QB    = OFF_WB + 6291456;         // 67108864
static constexpr size_t OFF_KB    = OFF_QB + 67108864;
static constexpr size_t OFF_VB    = OFF_KB + 67108864;
static constexpr size_t OFF_SC    = OFF_VB + 67108864;        // 2097152
static constexpr size_t OFF_U     = OFF_SC + 2097152;         // 256
static constexpr size_t OFF_SEL   = OFF_U + 256;              // 4096
static constexpr size_t OFF_SELQ  = OFF_SEL + 4096;           // 163840
static constexpr size_t OFF_PART  = OFF_SELQ + 163840;        // 64*10*64*66*4 = 10813440
static constexpr size_t OFF_AO    = OFF_PART + 10813440;      // 163840
static constexpr size_t OFF_CAND  = OFF_AO + 163840;          // 4096
static constexpr size_t OFF_CSC   = OFF_CAND + 4096;          // 8192
static constexpr size_t OFF_CQ    = OFF_CSC + 8192;           // 262144
static constexpr size_t WS_NEED   = OFF_CQ + 262144;

extern "C" void kernel_launch(void* const* d_in, const int* in_sizes, int n_in,
                              void* d_out, int out_size, void* d_ws, size_t ws_size,
                              hipStream_t stream)
{
    const float* x  = (const float*)d_in[0];
    const float* wq = (const float*)d_in[1];
    const float* bq = (const float*)d_in[2];
    const float* wk = (const float*)d_in[3];
    const float* bk = (const float*)d_in[4];
    const float* wv = (const float*)d_in[5];
    const float* bv = (const float*)d_in[6];
    const float* wo = (const float*)d_in[7];
    const float* bo = (const float*)d_in[8];
    float* out = (float*)d_out;

    if (ws_size < WS_NEED) return;

    char* ws = (char*)d_ws;
    unsigned short* xb = (unsigned short*)(ws + OFF_XB);
    unsigned short* wb = (unsigned short*)(ws + OFF_WB);
    unsigned short* Qb = (unsigned short*)(ws + OFF_QB);
    unsigned short* Kb = (unsigned short*)(ws + OFF_KB);
    unsigned short* Vb = (unsigned short*)(ws + OFF_VB);
    float*  scores = (float*)(ws + OFF_SC);
    int*    u      = (int*)(ws + OFF_U);
    int*    sel    = (int*)(ws + OFF_SEL);
    float*  selq   = (float*)(ws + OFF_SELQ);
    float*  part   = (float*)(ws + OFF_PART);
    float*  ao     = (float*)(ws + OFF_AO);
    int*    cand   = (int*)(ws + OFF_CAND);
    double* cscore = (double*)(ws + OFF_CSC);
    float*  cq     = (float*)(ws + OFF_CQ);

    k_conv_x   <<<32768, 256,  0, stream>>>(x, xb);
    k_conv_w   <<<3072,  256,  0, stream>>>(wq, wk, wv, wb);
    k_gemm_qkv <<<6144,  256,  0, stream>>>(xb, wb, bq, bk, bv, Qb, Kb, Vb);
    k_score    <<<2048,  256,  0, stream>>>(Qb, scores);
    k_stats    <<<4,     256,  0, stream>>>(scores, u);
    k_cand     <<<64,    1024, 0, stream>>>(scores, cand);
    k_rescore  <<<1024,  256,  0, stream>>>(cand, x, wq, bq, cscore, cq);
    k_select   <<<64,    64,   0, stream>>>(cand, cscore, cq, sel, selq);
    k_attn_part<<<2048,  256,  0, stream>>>(Kb, Vb, selq, u, part);
    k_merge    <<<640,   64,   0, stream>>>(part, u, ao);
    k_bias     <<<32768, 256,  0, stream>>>(bo, out);
    k_scatter  <<<640,   256,  0, stream>>>(ao, sel, u, wo, out);
}

// Round 4
// 737.157 us; speedup vs baseline: 2.3355x; 1.0267x over previous
//
#include <hip/hip_runtime.h>
#include <cmath>

// ---------------------------------------------------------------------------
// DynamicProbSparseAttention: B=4, L=8192, D=1024, H=16, dk=64
//   - bf16 MFMA GEMM for Q,K,V; Q never materialized: sparsity scores are
//     computed in the GEMM epilogue (quad-of-16 lanes hold whole Q rows)
//   - top-16 candidate prefilter (k_cand, fused u-stats)
//   - exact fp64 rescore of candidates (k_rescore), top-10 select (k_select)
//   - sparse attention: single-pass K/V, 2048 blocks
//   - output = broadcast bo + fused merge+scatter of (attn_out @ wo_head.T)
// ---------------------------------------------------------------------------

typedef short     s16x8 __attribute__((ext_vector_type(8)));
typedef unsigned short u16x8 __attribute__((ext_vector_type(8)));
typedef unsigned short u16x4 __attribute__((ext_vector_type(4)));
typedef float     f32x4 __attribute__((ext_vector_type(4)));

__device__ __forceinline__ unsigned short f2bf(float f) {
    unsigned u = __float_as_uint(f);
    u += 0x7fffu + ((u >> 16) & 1u);   // round-to-nearest-even
    return (unsigned short)(u >> 16);
}
__device__ __forceinline__ float bf2f(unsigned short s) {
    return __uint_as_float(((unsigned)s) << 16);
}

__device__ __forceinline__ void async16(const void* g, void* l) {
    __builtin_amdgcn_global_load_lds(
        (const __attribute__((address_space(1))) void*)g,
        (__attribute__((address_space(3))) void*)l, 16, 0, 0);
}

// ---------------- fused convert kernel (x + 3 weights) ----------------
__global__ void k_conv(const float* __restrict__ x, const float* __restrict__ wq,
                       const float* __restrict__ wk, const float* __restrict__ wv,
                       unsigned short* __restrict__ xb, unsigned short* __restrict__ wb) {
    size_t i = (size_t)blockIdx.x * 256 + threadIdx.x;    // 8388608 + 786432 float4s
    const float* src; unsigned short* dst; size_t idx;
    if (i < 8388608) { src = x; dst = xb; idx = i; }
    else {
        size_t j = i - 8388608;
        size_t wsel = j >> 18, rem = j & 262143;
        src = wsel == 0 ? wq : (wsel == 1 ? wk : wv);
        dst = wb + (j - rem - (wsel << 18)) * 0;   // base handled below
        dst = wb; idx = rem;
        ((ushort4*)dst)[j] = [&]{
            float4 v = ((const float4*)src)[rem];
            ushort4 o; o.x = f2bf(v.x); o.y = f2bf(v.y); o.z = f2bf(v.z); o.w = f2bf(v.w);
            return o; }();
        return;
    }
    float4 v = ((const float4*)src)[idx];
    ushort4 o; o.x = f2bf(v.x); o.y = f2bf(v.y); o.z = f2bf(v.z); o.w = f2bf(v.w);
    ((ushort4*)dst)[idx] = o;
}

// ---------------- fused QKV GEMM (C = x @ W^T + b), bf16 MFMA ----------------
// XCD-swizzled grid: all 24 blocks of an mt-tile land on one XCD.
// wsel==0 (Q): epilogue computes sparsity scores, Q never stored.
__global__ __launch_bounds__(256) void k_gemm_qkv(
    const unsigned short* __restrict__ xb, const unsigned short* __restrict__ wb,
    const float* __restrict__ bq, const float* __restrict__ bk, const float* __restrict__ bv,
    unsigned short* __restrict__ Kb, unsigned short* __restrict__ Vb,
    float* __restrict__ scores)
{
    __shared__ unsigned short As[128 * 32];
    __shared__ unsigned short Bs[128 * 32];
    int phys = blockIdx.x;
    int xcd = phys & 7, g = phys >> 3;            // 768 blocks per XCD
    int mt = xcd * 32 + g / 24, rem = g % 24;
    int wsel = rem >> 3, nt = rem & 7;
    const unsigned short* wbase = wb + ((size_t)wsel << 20) + ((size_t)nt * 128) * 1024;
    const float* bias = wsel == 0 ? bq : (wsel == 1 ? bk : bv);
    unsigned short* outp = wsel == 1 ? Kb : Vb;
    int tid = threadIdx.x, wave = tid >> 6, lane = tid & 63;
    int ml = lane & 15, quad = lane >> 4, wm = wave >> 1, wn = wave & 1;
    int lr = lane >> 2, lc = lane & 3;
    const unsigned short* xbase = xb + ((size_t)mt * 128) * 1024;

    f32x4 acc[4][4] = {};
    for (int k0 = 0; k0 < 1024; k0 += 32) {
#pragma unroll
        for (int s = 0; s < 2; ++s) {
            int seg = wave * 2 + s;
            int row = seg * 16 + lr;
            async16(xbase + (size_t)row * 1024 + k0 + lc * 8, &As[seg * 512]);
            async16(wbase + (size_t)row * 1024 + k0 + lc * 8, &Bs[seg * 512]);
        }
        __builtin_amdgcn_s_waitcnt(0);
        __syncthreads();
        s16x8 a[4], b[4];
#pragma unroll
        for (int i = 0; i < 4; ++i) a[i] = *(const s16x8*)&As[(wm * 64 + i * 16 + ml) * 32 + quad * 8];
#pragma unroll
        for (int j = 0; j < 4; ++j) b[j] = *(const s16x8*)&Bs[(wn * 64 + j * 16 + ml) * 32 + quad * 8];
#pragma unroll
        for (int i = 0; i < 4; ++i)
#pragma unroll
            for (int j = 0; j < 4; ++j)
                acc[i][j] = __builtin_amdgcn_mfma_f32_16x16x32_bf16(a[i], b[j], acc[i][j], 0, 0, 0);
        __syncthreads();
    }

    float bvv[4];
#pragma unroll
    for (int j = 0; j < 4; ++j) bvv[j] = bias[nt * 128 + wn * 64 + j * 16 + ml];

    if (wsel == 0) {
        // score epilogue: quad's 16 lanes hold full 64-wide Q rows of head hh
        int hh = nt * 2 + wn;
#pragma unroll
        for (int i = 0; i < 4; ++i) {
#pragma unroll
            for (int r = 0; r < 4; ++r) {
                float q0 = acc[i][0][r] + bvv[0];
                float q1 = acc[i][1][r] + bvv[1];
                float q2 = acc[i][2][r] + bvv[2];
                float q3 = acc[i][3][r] + bvv[3];
                float mx = fmaxf(fmaxf(q0, q1), fmaxf(q2, q3));
                float sm = q0 + q1 + q2 + q3;
                float ss = q0 * q0 + q1 * q1 + q2 * q2 + q3 * q3;
#pragma unroll
                for (int off = 1; off < 16; off <<= 1) {
                    mx = fmaxf(mx, __shfl_xor(mx, off));
                    sm += __shfl_xor(sm, off);
                    ss += __shfl_xor(ss, off);
                }
                float e0 = expf(q0 - mx), e1 = expf(q1 - mx);
                float e2 = expf(q2 - mx), e3 = expf(q3 - mx);
                float S = e0 + e1 + e2 + e3;
#pragma unroll
                for (int off = 1; off < 16; off <<= 1) S += __shfl_xor(S, off);
                float is = 1.f / S;
                float p0 = e0 * is, p1 = e1 * is, p2 = e2 * is, p3 = e3 * is;
                float ent = -p0 * logf(p0 + 1e-9f) - p1 * logf(p1 + 1e-9f)
                            - p2 * logf(p2 + 1e-9f) - p3 * logf(p3 + 1e-9f);
                float mean = sm * (1.f / 64.f);
                float d0 = q0 - mean, d1 = q1 - mean, d2 = q2 - mean, d3 = q3 - mean;
                float var = d0 * d0 + d1 * d1 + d2 * d2 + d3 * d3;
#pragma unroll
                for (int off = 1; off < 16; off <<= 1) {
                    ent += __shfl_xor(ent, off);
                    var += __shfl_xor(var, off);
                }
                if (ml == 0) {
                    float sc = 0.5f * sqrtf(ss) + 0.3f * ent + 0.2f * (var * (1.f / 63.f));
                    int row = mt * 128 + wm * 64 + i * 16 + quad * 4 + r;
                    scores[(size_t)(((row >> 13) << 4) + hh) * 8192 + (row & 8191)] = sc;
                }
            }
        }
    } else {
#pragma unroll
        for (int i = 0; i < 4; ++i) {
            int grow0 = mt * 128 + wm * 64 + i * 16 + quad * 4;
#pragma unroll
            for (int j = 0; j < 4; ++j) {
                int gcol = nt * 128 + wn * 64 + j * 16 + ml;
#pragma unroll
                for (int r = 0; r < 4; ++r)
                    outp[(size_t)(grow0 + r) * 1024 + gcol] = f2bf(acc[i][j][r] + bvv[j]);
            }
        }
    }
}

// ---------------- top-16 candidates + (h==0) u-stats, per pair ----------------
__global__ __launch_bounds__(1024) void k_cand(const float* __restrict__ scores,
                                               int* __restrict__ cand, int* __restrict__ u)
{
    int pair = blockIdx.x; int t = threadIdx.x;
    __shared__ float  s_lds[8192];
    __shared__ double dred[1024];
    __shared__ float  wvv[16];
    __shared__ int    wii[16];
    const float* sp = scores + (size_t)pair * 8192;
    for (int i = t; i < 8192; i += 1024) s_lds[i] = sp[i];
    __syncthreads();

    if ((pair & 15) == 0) {     // head 0: compute u[b] from these scores
        double a0 = 0;
#pragma unroll
        for (int k = 0; k < 8; ++k) a0 += (double)s_lds[t + k * 1024];
        dred[t] = a0; __syncthreads();
        for (int st = 512; st > 0; st >>= 1) { if (t < st) dred[t] += dred[t + st]; __syncthreads(); }
        double mean = dred[0] / 8192.0;
        __syncthreads();
        double a1 = 0;
#pragma unroll
        for (int k = 0; k < 8; ++k) { double d = (double)s_lds[t + k * 1024] - mean; a1 += d * d; }
        dred[t] = a1; __syncthreads();
        for (int st = 512; st > 0; st >>= 1) { if (t < st) dred[t] += dred[t + st]; __syncthreads(); }
        if (t == 0) {
            double sd = sqrt(dred[0] / 8191.0);
            double ratio = sd / (mean + 1e-6) * 10.0;
            int f = (int)rint(ratio);
            f = f < 3 ? 3 : (f > 10 ? 10 : f);
            u[pair >> 4] = f;
        }
        __syncthreads();
    }

    for (int it = 0; it < 16; ++it) {
        float bv = -1e30f; int bi = 0x7fffffff;
#pragma unroll
        for (int k = 0; k < 8; ++k) {
            int i = t + k * 1024;
            float v = s_lds[i];
            if (v > bv || (v == bv && i < bi)) { bv = v; bi = i; }
        }
#pragma unroll
        for (int off = 32; off > 0; off >>= 1) {
            float ov = __shfl_down(bv, off);
            int   oi = __shfl_down(bi, off);
            if (ov > bv || (ov == bv && oi < bi)) { bv = ov; bi = oi; }
        }
        if ((t & 63) == 0) { wvv[t >> 6] = bv; wii[t >> 6] = bi; }
        __syncthreads();
        if (t == 0) {
            float fv = wvv[0]; int fi = wii[0];
            for (int k = 1; k < 16; ++k)
                if (wvv[k] > fv || (wvv[k] == fv && wii[k] < fi)) { fv = wvv[k]; fi = wii[k]; }
            cand[pair * 16 + it] = fi;
            s_lds[fi] = -1e30f;
        }
        __syncthreads();
    }
}

// ---------------- exact fp64 rescore, one block per (pair,candidate) ----------------
__global__ __launch_bounds__(256) void k_rescore(
    const int* __restrict__ cand, const float* __restrict__ x,
    const float* __restrict__ wq, const float* __restrict__ bq,
    double* __restrict__ cscore, float* __restrict__ cq)
{
    int bid = blockIdx.x;             // pair*16 + c
    int pair = bid >> 4;
    int b = pair >> 4, h = pair & 15;
    int t = threadIdx.x;
    __shared__ float  xrow[1024];
    __shared__ double dred[256];
    __shared__ double qrow[64];

    int l = cand[bid];
    const float* xr = x + ((size_t)b * 8192 + l) * 1024;
    for (int i = t; i < 1024; i += 256) xrow[i] = xr[i];
    __syncthreads();

    int d = t >> 2, ks = t & 3;
    const float* wr = wq + (size_t)(h * 64 + d) * 1024 + ks * 256;
    const float* xs = xrow + ks * 256;
    double p = 0;
    for (int k = 0; k < 256; k += 4) {
        float4 w4 = *(const float4*)(wr + k);
        float4 x4 = *(const float4*)(xs + k);
        p += (double)w4.x * x4.x + (double)w4.y * x4.y +
             (double)w4.z * x4.z + (double)w4.w * x4.w;
    }
    dred[t] = p; __syncthreads();
    if ((t & 3) == 0)
        qrow[t >> 2] = dred[t] + dred[t + 1] + dred[t + 2] + dred[t + 3] + (double)bq[h * 64 + (t >> 2)];
    __syncthreads();

    if (t < 64) {
        double q = qrow[t];
        cq[(size_t)bid * 64 + t] = (float)q;
        double m = q;
#pragma unroll
        for (int off = 32; off > 0; off >>= 1) m = fmax(m, __shfl_down(m, off));
        m = __shfl(m, 0);
        double e = exp(q - m);
        double sum = q, sumsq = q * q, S = e;
#pragma unroll
        for (int off = 32; off > 0; off >>= 1) {
            sum += __shfl_down(sum, off);
            sumsq += __shfl_down(sumsq, off);
            S += __shfl_down(S, off);
        }
        sum = __shfl(sum, 0); sumsq = __shfl(sumsq, 0); S = __shfl(S, 0);
        double pp = e / S;
        double entc = -pp * log(pp + 1e-9);
        double mean = sum / 64.0;
        double dv = q - mean;
        double varc = dv * dv;
#pragma unroll
        for (int off = 32; off > 0; off >>= 1) {
            entc += __shfl_down(entc, off);
            varc += __shfl_down(varc, off);
        }
        if (t == 0)
            cscore[bid] = 0.5 * sqrt(sumsq) + 0.3 * entc + 0.2 * (varc / 63.0);
    }
}

// ---------------- top-10-of-16 select ----------------
__global__ void k_select(const int* __restrict__ cand, const double* __restrict__ cscore,
                         const float* __restrict__ cq,
                         int* __restrict__ sel, float* __restrict__ selq)
{
    int pair = blockIdx.x; int t = threadIdx.x;   // 64 threads
    __shared__ int order[10];
    if (t == 0) {
        bool used[16] = {};
        for (int r = 0; r < 10; ++r) {
            int best = -1;
            for (int c = 0; c < 16; ++c) {
                if (used[c]) continue;
                int ic = pair * 16 + c;
                if (best < 0 || cscore[ic] > cscore[pair * 16 + best] ||
                    (cscore[ic] == cscore[pair * 16 + best] && cand[ic] < cand[pair * 16 + best]))
                    best = c;
            }
            used[best] = true; order[r] = best;
            sel[pair * 10 + r] = cand[pair * 16 + best];
        }
    }
    __syncthreads();
    for (int r = 0; r < 10; ++r)
        selq[((size_t)pair * 10 + r) * 64 + t] = cq[((size_t)pair * 16 + order[r]) * 64 + t];
}

// ---------------- attention partials: one K/V pass, 256-row chunks ----------------
__global__ __launch_bounds__(256) void k_attn_part(
    const unsigned short* __restrict__ Kb, const unsigned short* __restrict__ Vb,
    const float* __restrict__ selq, const int* __restrict__ u,
    float* __restrict__ part)
{
    int bid = blockIdx.x;
    int pair = bid >> 5, chunk = bid & 31;
    int b = pair >> 4, h = pair & 15;
    int uu = u[b];
    int t = threadIdx.x, wave = t >> 6, lane = t & 63;

    __shared__ float q_sh[10][64];
    __shared__ float w_sh[10][256];
    __shared__ unsigned short V_sh[256][68];
    __shared__ float mc_sh[10][2], Sc_sh[10][2];

    size_t kvbase = ((size_t)b * 8192 + (size_t)chunk * 256) * 1024 + h * 64;

    for (int i = t; i < uu * 64; i += 256)
        q_sh[i >> 6][i & 63] = selq[(size_t)pair * 640 + i] * 0.125f;

    const u16x8* kr = (const u16x8*)(Kb + kvbase + (size_t)t * 1024);
    const u16x8* vr = (const u16x8*)(Vb + kvbase + (size_t)t * 1024);
    u16x8 vreg[8];
#pragma unroll
    for (int k8 = 0; k8 < 8; ++k8) vreg[k8] = vr[k8];
#pragma unroll
    for (int k8 = 0; k8 < 8; ++k8) {
        *(u16x4*)&V_sh[t][k8 * 8]     = { vreg[k8][0], vreg[k8][1], vreg[k8][2], vreg[k8][3] };
        *(u16x4*)&V_sh[t][k8 * 8 + 4] = { vreg[k8][4], vreg[k8][5], vreg[k8][6], vreg[k8][7] };
    }
    float krow[64];
#pragma unroll
    for (int k8 = 0; k8 < 8; ++k8) {
        u16x8 kv = kr[k8];
#pragma unroll
        for (int e = 0; e < 8; ++e) krow[k8 * 8 + e] = bf2f(kv[e]);
    }
    __syncthreads();

    for (int rr = 0; rr < uu; ++rr) {
        const float4* qp = (const float4*)q_sh[rr];
        float acc = 0.f;
#pragma unroll
        for (int i4 = 0; i4 < 16; ++i4) {
            float4 q4 = qp[i4];
            acc += q4.x * krow[i4 * 4] + q4.y * krow[i4 * 4 + 1] +
                   q4.z * krow[i4 * 4 + 2] + q4.w * krow[i4 * 4 + 3];
        }
        w_sh[rr][t] = acc;
    }
    __syncthreads();

    for (int rr = wave; rr < uu; rr += 4) {
        float4 wv = *(const float4*)&w_sh[rr][lane * 4];
        float m4 = fmaxf(fmaxf(wv.x, wv.y), fmaxf(wv.z, wv.w));
#pragma unroll
        for (int off = 16; off > 0; off >>= 1) m4 = fmaxf(m4, __shfl_xor(m4, off));
        float e0 = expf(wv.x - m4), e1 = expf(wv.y - m4);
        float e2 = expf(wv.z - m4), e3 = expf(wv.w - m4);
        float s = e0 + e1 + e2 + e3;
#pragma unroll
        for (int off = 16; off > 0; off >>= 1) s += __shfl_xor(s, off);
        float4 ev = { e0, e1, e2, e3 };
        *(float4*)&w_sh[rr][lane * 4] = ev;
        if ((lane & 31) == 0) { int jh = lane >> 5; mc_sh[rr][jh] = m4; Sc_sh[rr][jh] = s; }
    }
    __syncthreads();

    int jh = t >> 7, tt = t & 127, dp = tt & 31;
    for (int rr = tt >> 5; rr < uu; rr += 4) {
        float o0 = 0.f, o1 = 0.f;
        int j0 = jh * 128;
        for (int j = j0; j < j0 + 128; j += 4) {
            float4 w4 = *(const float4*)&w_sh[rr][j];
#pragma unroll
            for (int jj = 0; jj < 4; ++jj) {
                unsigned v = *(const unsigned*)&V_sh[j + jj][dp * 2];
                float w1 = jj == 0 ? w4.x : (jj == 1 ? w4.y : (jj == 2 ? w4.z : w4.w));
                o0 += w1 * __uint_as_float(v << 16);
                o1 += w1 * __uint_as_float(v & 0xffff0000u);
            }
        }
        float* pp = part + (((size_t)pair * 10 + rr) * 64 + chunk * 2 + jh) * 66;
        float2 o2 = { o0, o1 };
        *(float2*)&pp[2 + dp * 2] = o2;
        if (dp == 0) { pp[0] = mc_sh[rr][jh]; pp[1] = Sc_sh[rr][jh]; }
    }
}

// ---------------- output: broadcast bias ----------------
__global__ void k_bias(const float* __restrict__ bo, float* __restrict__ out) {
    size_t i = (size_t)blockIdx.x * 256 + threadIdx.x;   // 8388608 float4s
    int col4 = (int)(i & 255);
    ((float4*)out)[i] = ((const float4*)bo)[col4];
}

// ---------------- fused merge + sparse scatter ----------------
__global__ __launch_bounds__(256) void k_mergescatter(
    const float* __restrict__ part, const int* __restrict__ sel,
    const int* __restrict__ u, const float* __restrict__ wo,
    float* __restrict__ out)
{
    int idx = blockIdx.x; int pair = idx / 10; int r = idx % 10;
    int b = pair >> 4, h = pair & 15;
    if (r >= u[b]) return;
    int t = threadIdx.x;
    __shared__ float a_sh[64];
    if (t < 64) {
        const float* base = part + ((size_t)pair * 10 + r) * 64 * 66;
        float m = -1e30f;
        for (int c = 0; c < 64; ++c) m = fmaxf(m, base[c * 66]);
        float S = 0, o = 0;
        for (int c = 0; c < 64; ++c) {
            float f = expf(base[c * 66] - m);
            S += f * base[c * 66 + 1];
            o += f * base[c * 66 + 2 + t];
        }
        a_sh[t] = o / S;
    }
    __syncthreads();
    int l = sel[pair * 10 + r];
    float* orow = out + ((size_t)b * 8192 + l) * 1024;
    for (int j = t; j < 1024; j += 256) {
        const float* wr = wo + (size_t)j * 1024 + h * 64;
        float acc = 0;
#pragma unroll
        for (int d = 0; d < 64; d += 4) {
            float4 w4 = *(const float4*)(wr + d);
            acc += a_sh[d] * w4.x + a_sh[d + 1] * w4.y + a_sh[d + 2] * w4.z + a_sh[d + 3] * w4.w;
        }
        atomicAdd(orow + j, acc);
    }
}

// ---------------- workspace layout ----------------
static constexpr size_t OFF_XB    = 0;                        // 67108864
static constexpr size_t OFF_WB    = OFF_XB + 67108864;        // 6291456
static constexpr size_t OFF_KB    = OFF_WB + 6291456;         // 67108864
static constexpr size_t OFF_VB    = OFF_KB + 67108864;        // 67108864
static constexpr size_t OFF_SC    = OFF_VB + 67108864;        // 2097152
static constexpr size_t OFF_U     = OFF_SC + 2097152;         // 256
static constexpr size_t OFF_SEL   = OFF_U + 256;              // 4096
static constexpr size_t OFF_SELQ  = OFF_SEL + 4096;           // 163840
static constexpr size_t OFF_PART  = OFF_SELQ + 163840;        // 64*10*64*66*4 = 10813440
static constexpr size_t OFF_CAND  = OFF_PART + 10813440;      // 4096
static constexpr size_t OFF_CSC   = OFF_CAND + 4096;          // 8192
static constexpr size_t OFF_CQ    = OFF_CSC + 8192;           // 262144
static constexpr size_t WS_NEED   = OFF_CQ + 262144;

extern "C" void kernel_launch(void* const* d_in, const int* in_sizes, int n_in,
                              void* d_out, int out_size, void* d_ws, size_t ws_size,
                              hipStream_t stream)
{
    const float* x  = (const float*)d_in[0];
    const float* wq = (const float*)d_in[1];
    const float* bq = (const float*)d_in[2];
    const float* wk = (const float*)d_in[3];
    const float* bk = (const float*)d_in[4];
    const float* wv = (const float*)d_in[5];
    const float* bv = (const float*)d_in[6];
    const float* wo = (const float*)d_in[7];
    const float* bo = (const float*)d_in[8];
    float* out = (float*)d_out;

    if (ws_size < WS_NEED) return;

    char* ws = (char*)d_ws;
    unsigned short* xb = (unsigned short*)(ws + OFF_XB);
    unsigned short* wb = (unsigned short*)(ws + OFF_WB);
    unsigned short* Kb = (unsigned short*)(ws + OFF_KB);
    unsigned short* Vb = (unsigned short*)(ws + OFF_VB);
    float*  scores = (float*)(ws + OFF_SC);
    int*    u      = (int*)(ws + OFF_U);
    int*    sel    = (int*)(ws + OFF_SEL);
    float*  selq   = (float*)(ws + OFF_SELQ);
    float*  part   = (float*)(ws + OFF_PART);
    int*    cand   = (int*)(ws + OFF_CAND);
    double* cscore = (double*)(ws + OFF_CSC);
    float*  cq     = (float*)(ws + OFF_CQ);

    k_conv        <<<35840, 256,  0, stream>>>(x, wq, wk, wv, xb, wb);
    k_gemm_qkv    <<<6144,  256,  0, stream>>>(xb, wb, bq, bk, bv, Kb, Vb, scores);
    k_cand        <<<64,    1024, 0, stream>>>(scores, cand, u);
    k_rescore     <<<1024,  256,  0, stream>>>(cand, x, wq, bq, cscore, cq);
    k_select      <<<64,    64,   0, stream>>>(cand, cscore, cq, sel, selq);
    k_attn_part   <<<2048,  256,  0, stream>>>(Kb, Vb, selq, u, part);
    k_bias        <<<32768, 256,  0, stream>>>(bo, out);
    k_mergescatter<<<640,   256,  0, stream>>>(part, sel, u, wo, out);
}

// Round 5
// 733.767 us; speedup vs baseline: 2.3463x; 1.0046x over previous
//
#include <hip/hip_runtime.h>
#include <cmath>

// ---------------------------------------------------------------------------
// DynamicProbSparseAttention: B=4, L=8192, D=1024, H=16, dk=64
//   - bf16 MFMA GEMM for Q,K,V; Q never materialized: sparsity scores are
//     computed in the GEMM epilogue (quad-of-16 lanes hold whole Q rows)
//   - natural block order (24 consecutive blocks share one mt x-tile;
//     XCD swizzle measured WORSE: FETCH 287->530 MB in R4)
//   - top-16 candidate prefilter (k_cand, fused u-stats)
//   - exact fp64 rescore of candidates (k_rescore), top-10 select (k_select)
//   - sparse attention: single-pass K/V, 2048 blocks
//   - output = broadcast bo + fused merge+scatter of (attn_out @ wo_head.T)
// ---------------------------------------------------------------------------

typedef short     s16x8 __attribute__((ext_vector_type(8)));
typedef unsigned short u16x8 __attribute__((ext_vector_type(8)));
typedef unsigned short u16x4 __attribute__((ext_vector_type(4)));
typedef float     f32x4 __attribute__((ext_vector_type(4)));

__device__ __forceinline__ unsigned short f2bf(float f) {
    unsigned u = __float_as_uint(f);
    u += 0x7fffu + ((u >> 16) & 1u);   // round-to-nearest-even
    return (unsigned short)(u >> 16);
}
__device__ __forceinline__ float bf2f(unsigned short s) {
    return __uint_as_float(((unsigned)s) << 16);
}

__device__ __forceinline__ void async16(const void* g, void* l) {
    __builtin_amdgcn_global_load_lds(
        (const __attribute__((address_space(1))) void*)g,
        (__attribute__((address_space(3))) void*)l, 16, 0, 0);
}

// ---------------- fused convert kernel (x + 3 weights) ----------------
__global__ void k_conv(const float* __restrict__ x, const float* __restrict__ wq,
                       const float* __restrict__ wk, const float* __restrict__ wv,
                       unsigned short* __restrict__ xb, unsigned short* __restrict__ wb) {
    size_t i = (size_t)blockIdx.x * 256 + threadIdx.x;    // 8388608 + 786432 float4s
    if (i < 8388608) {
        float4 v = ((const float4*)x)[i];
        ushort4 o; o.x = f2bf(v.x); o.y = f2bf(v.y); o.z = f2bf(v.z); o.w = f2bf(v.w);
        ((ushort4*)xb)[i] = o;
    } else {
        size_t j = i - 8388608;
        size_t wsel = j >> 18, rem = j & 262143;
        const float* src = wsel == 0 ? wq : (wsel == 1 ? wk : wv);
        float4 v = ((const float4*)src)[rem];
        ushort4 o; o.x = f2bf(v.x); o.y = f2bf(v.y); o.z = f2bf(v.z); o.w = f2bf(v.w);
        ((ushort4*)wb)[j] = o;
    }
}

// ---------------- fused QKV GEMM (C = x @ W^T + b), bf16 MFMA ----------------
// wsel==0 (Q): epilogue computes sparsity scores, Q never stored.
__global__ __launch_bounds__(256) void k_gemm_qkv(
    const unsigned short* __restrict__ xb, const unsigned short* __restrict__ wb,
    const float* __restrict__ bq, const float* __restrict__ bk, const float* __restrict__ bv,
    unsigned short* __restrict__ Kb, unsigned short* __restrict__ Vb,
    float* __restrict__ scores)
{
    __shared__ unsigned short As[128 * 32];
    __shared__ unsigned short Bs[128 * 32];
    int bid = blockIdx.x;
    int mt = bid / 24, rem = bid % 24;            // natural order: 24 blocks share mt
    int wsel = rem >> 3, nt = rem & 7;
    const unsigned short* wbase = wb + ((size_t)wsel << 20) + ((size_t)nt * 128) * 1024;
    const float* bias = wsel == 0 ? bq : (wsel == 1 ? bk : bv);
    unsigned short* outp = wsel == 1 ? Kb : Vb;
    int tid = threadIdx.x, wave = tid >> 6, lane = tid & 63;
    int ml = lane & 15, quad = lane >> 4, wm = wave >> 1, wn = wave & 1;
    int lr = lane >> 2, lc = lane & 3;
    const unsigned short* xbase = xb + ((size_t)mt * 128) * 1024;

    f32x4 acc[4][4] = {};
    for (int k0 = 0; k0 < 1024; k0 += 32) {
#pragma unroll
        for (int s = 0; s < 2; ++s) {
            int seg = wave * 2 + s;
            int row = seg * 16 + lr;
            async16(xbase + (size_t)row * 1024 + k0 + lc * 8, &As[seg * 512]);
            async16(wbase + (size_t)row * 1024 + k0 + lc * 8, &Bs[seg * 512]);
        }
        __builtin_amdgcn_s_waitcnt(0);
        __syncthreads();
        s16x8 a[4], b[4];
#pragma unroll
        for (int i = 0; i < 4; ++i) a[i] = *(const s16x8*)&As[(wm * 64 + i * 16 + ml) * 32 + quad * 8];
#pragma unroll
        for (int j = 0; j < 4; ++j) b[j] = *(const s16x8*)&Bs[(wn * 64 + j * 16 + ml) * 32 + quad * 8];
#pragma unroll
        for (int i = 0; i < 4; ++i)
#pragma unroll
            for (int j = 0; j < 4; ++j)
                acc[i][j] = __builtin_amdgcn_mfma_f32_16x16x32_bf16(a[i], b[j], acc[i][j], 0, 0, 0);
        __syncthreads();
    }

    float bvv[4];
#pragma unroll
    for (int j = 0; j < 4; ++j) bvv[j] = bias[nt * 128 + wn * 64 + j * 16 + ml];

    if (wsel == 0) {
        // score epilogue: quad's 16 lanes hold full 64-wide Q rows of head hh
        int hh = nt * 2 + wn;
#pragma unroll
        for (int i = 0; i < 4; ++i) {
#pragma unroll
            for (int r = 0; r < 4; ++r) {
                float q0 = acc[i][0][r] + bvv[0];
                float q1 = acc[i][1][r] + bvv[1];
                float q2 = acc[i][2][r] + bvv[2];
                float q3 = acc[i][3][r] + bvv[3];
                float mx = fmaxf(fmaxf(q0, q1), fmaxf(q2, q3));
                float sm = q0 + q1 + q2 + q3;
                float ss = q0 * q0 + q1 * q1 + q2 * q2 + q3 * q3;
#pragma unroll
                for (int off = 1; off < 16; off <<= 1) {
                    mx = fmaxf(mx, __shfl_xor(mx, off));
                    sm += __shfl_xor(sm, off);
                    ss += __shfl_xor(ss, off);
                }
                float e0 = expf(q0 - mx), e1 = expf(q1 - mx);
                float e2 = expf(q2 - mx), e3 = expf(q3 - mx);
                float S = e0 + e1 + e2 + e3;
#pragma unroll
                for (int off = 1; off < 16; off <<= 1) S += __shfl_xor(S, off);
                float is = 1.f / S;
                float p0 = e0 * is, p1 = e1 * is, p2 = e2 * is, p3 = e3 * is;
                float ent = -p0 * logf(p0 + 1e-9f) - p1 * logf(p1 + 1e-9f)
                            - p2 * logf(p2 + 1e-9f) - p3 * logf(p3 + 1e-9f);
                float mean = sm * (1.f / 64.f);
                float d0 = q0 - mean, d1 = q1 - mean, d2 = q2 - mean, d3 = q3 - mean;
                float var = d0 * d0 + d1 * d1 + d2 * d2 + d3 * d3;
#pragma unroll
                for (int off = 1; off < 16; off <<= 1) {
                    ent += __shfl_xor(ent, off);
                    var += __shfl_xor(var, off);
                }
                if (ml == 0) {
                    float sc = 0.5f * sqrtf(ss) + 0.3f * ent + 0.2f * (var * (1.f / 63.f));
                    int row = mt * 128 + wm * 64 + i * 16 + quad * 4 + r;
                    scores[(size_t)(((row >> 13) << 4) + hh) * 8192 + (row & 8191)] = sc;
                }
            }
        }
    } else {
#pragma unroll
        for (int i = 0; i < 4; ++i) {
            int grow0 = mt * 128 + wm * 64 + i * 16 + quad * 4;
#pragma unroll
            for (int j = 0; j < 4; ++j) {
                int gcol = nt * 128 + wn * 64 + j * 16 + ml;
#pragma unroll
                for (int r = 0; r < 4; ++r)
                    outp[(size_t)(grow0 + r) * 1024 + gcol] = f2bf(acc[i][j][r] + bvv[j]);
            }
        }
    }
}

// ---------------- top-16 candidates + (h==0) u-stats, per pair ----------------
__global__ __launch_bounds__(1024) void k_cand(const float* __restrict__ scores,
                                               int* __restrict__ cand, int* __restrict__ u)
{
    int pair = blockIdx.x; int t = threadIdx.x;
    __shared__ float  s_lds[8192];
    __shared__ double dred[1024];
    __shared__ float  wvv[16];
    __shared__ int    wii[16];
    const float* sp = scores + (size_t)pair * 8192;
    for (int i = t; i < 8192; i += 1024) s_lds[i] = sp[i];
    __syncthreads();

    if ((pair & 15) == 0) {     // head 0: compute u[b] from these scores
        double a0 = 0;
#pragma unroll
        for (int k = 0; k < 8; ++k) a0 += (double)s_lds[t + k * 1024];
        dred[t] = a0; __syncthreads();
        for (int st = 512; st > 0; st >>= 1) { if (t < st) dred[t] += dred[t + st]; __syncthreads(); }
        double mean = dred[0] / 8192.0;
        __syncthreads();
        double a1 = 0;
#pragma unroll
        for (int k = 0; k < 8; ++k) { double d = (double)s_lds[t + k * 1024] - mean; a1 += d * d; }
        dred[t] = a1; __syncthreads();
        for (int st = 512; st > 0; st >>= 1) { if (t < st) dred[t] += dred[t + st]; __syncthreads(); }
        if (t == 0) {
            double sd = sqrt(dred[0] / 8191.0);
            double ratio = sd / (mean + 1e-6) * 10.0;
            int f = (int)rint(ratio);
            f = f < 3 ? 3 : (f > 10 ? 10 : f);
            u[pair >> 4] = f;
        }
        __syncthreads();
    }

    for (int it = 0; it < 16; ++it) {
        float bv = -1e30f; int bi = 0x7fffffff;
#pragma unroll
        for (int k = 0; k < 8; ++k) {
            int i = t + k * 1024;
            float v = s_lds[i];
            if (v > bv || (v == bv && i < bi)) { bv = v; bi = i; }
        }
#pragma unroll
        for (int off = 32; off > 0; off >>= 1) {
            float ov = __shfl_down(bv, off);
            int   oi = __shfl_down(bi, off);
            if (ov > bv || (ov == bv && oi < bi)) { bv = ov; bi = oi; }
        }
        if ((t & 63) == 0) { wvv[t >> 6] = bv; wii[t >> 6] = bi; }
        __syncthreads();
        if (t == 0) {
            float fv = wvv[0]; int fi = wii[0];
            for (int k = 1; k < 16; ++k)
                if (wvv[k] > fv || (wvv[k] == fv && wii[k] < fi)) { fv = wvv[k]; fi = wii[k]; }
            cand[pair * 16 + it] = fi;
            s_lds[fi] = -1e30f;
        }
        __syncthreads();
    }
}

// ---------------- exact fp64 rescore, one block per (pair,candidate) ----------------
__global__ __launch_bounds__(256) void k_rescore(
    const int* __restrict__ cand, const float* __restrict__ x,
    const float* __restrict__ wq, const float* __restrict__ bq,
    double* __restrict__ cscore, float* __restrict__ cq)
{
    int bid = blockIdx.x;             // pair*16 + c
    int pair = bid >> 4;
    int b = pair >> 4, h = pair & 15;
    int t = threadIdx.x;
    __shared__ float  xrow[1024];
    __shared__ double dred[256];
    __shared__ double qrow[64];

    int l = cand[bid];
    const float* xr = x + ((size_t)b * 8192 + l) * 1024;
    for (int i = t; i < 1024; i += 256) xrow[i] = xr[i];
    __syncthreads();

    int d = t >> 2, ks = t & 3;
    const float* wr = wq + (size_t)(h * 64 + d) * 1024 + ks * 256;
    const float* xs = xrow + ks * 256;
    double p = 0;
    for (int k = 0; k < 256; k += 4) {
        float4 w4 = *(const float4*)(wr + k);
        float4 x4 = *(const float4*)(xs + k);
        p += (double)w4.x * x4.x + (double)w4.y * x4.y +
             (double)w4.z * x4.z + (double)w4.w * x4.w;
    }
    dred[t] = p; __syncthreads();
    if ((t & 3) == 0)
        qrow[t >> 2] = dred[t] + dred[t + 1] + dred[t + 2] + dred[t + 3] + (double)bq[h * 64 + (t >> 2)];
    __syncthreads();

    if (t < 64) {
        double q = qrow[t];
        cq[(size_t)bid * 64 + t] = (float)q;
        double m = q;
#pragma unroll
        for (int off = 32; off > 0; off >>= 1) m = fmax(m, __shfl_down(m, off));
        m = __shfl(m, 0);
        double e = exp(q - m);
        double sum = q, sumsq = q * q, S = e;
#pragma unroll
        for (int off = 32; off > 0; off >>= 1) {
            sum += __shfl_down(sum, off);
            sumsq += __shfl_down(sumsq, off);
            S += __shfl_down(S, off);
        }
        sum = __shfl(sum, 0); sumsq = __shfl(sumsq, 0); S = __shfl(S, 0);
        double pp = e / S;
        double entc = -pp * log(pp + 1e-9);
        double mean = sum / 64.0;
        double dv = q - mean;
        double varc = dv * dv;
#pragma unroll
        for (int off = 32; off > 0; off >>= 1) {
            entc += __shfl_down(entc, off);
            varc += __shfl_down(varc, off);
        }
        if (t == 0)
            cscore[bid] = 0.5 * sqrt(sumsq) + 0.3 * entc + 0.2 * (varc / 63.0);
    }
}

// ---------------- top-10-of-16 select ----------------
__global__ void k_select(const int* __restrict__ cand, const double* __restrict__ cscore,
                         const float* __restrict__ cq,
                         int* __restrict__ sel, float* __restrict__ selq)
{
    int pair = blockIdx.x; int t = threadIdx.x;   // 64 threads
    __shared__ int order[10];
    if (t == 0) {
        bool used[16] = {};
        for (int r = 0; r < 10; ++r) {
            int best = -1;
            for (int c = 0; c < 16; ++c) {
                if (used[c]) continue;
                int ic = pair * 16 + c;
                if (best < 0 || cscore[ic] > cscore[pair * 16 + best] ||
                    (cscore[ic] == cscore[pair * 16 + best] && cand[ic] < cand[pair * 16 + best]))
                    best = c;
            }
            used[best] = true; order[r] = best;
            sel[pair * 10 + r] = cand[pair * 16 + best];
        }
    }
    __syncthreads();
    for (int r = 0; r < 10; ++r)
        selq[((size_t)pair * 10 + r) * 64 + t] = cq[((size_t)pair * 16 + order[r]) * 64 + t];
}

// ---------------- attention partials: one K/V pass, 256-row chunks ----------------
__global__ __launch_bounds__(256) void k_attn_part(
    const unsigned short* __restrict__ Kb, const unsigned short* __restrict__ Vb,
    const float* __restrict__ selq, const int* __restrict__ u,
    float* __restrict__ part)
{
    int bid = blockIdx.x;
    int pair = bid >> 5, chunk = bid & 31;
    int b = pair >> 4, h = pair & 15;
    int uu = u[b];
    int t = threadIdx.x, wave = t >> 6, lane = t & 63;

    __shared__ float q_sh[10][64];
    __shared__ float w_sh[10][256];
    __shared__ unsigned short V_sh[256][68];
    __shared__ float mc_sh[10][2], Sc_sh[10][2];

    size_t kvbase = ((size_t)b * 8192 + (size_t)chunk * 256) * 1024 + h * 64;

    for (int i = t; i < uu * 64; i += 256)
        q_sh[i >> 6][i & 63] = selq[(size_t)pair * 640 + i] * 0.125f;

    const u16x8* kr = (const u16x8*)(Kb + kvbase + (size_t)t * 1024);
    const u16x8* vr = (const u16x8*)(Vb + kvbase + (size_t)t * 1024);
    u16x8 vreg[8];
#pragma unroll
    for (int k8 = 0; k8 < 8; ++k8) vreg[k8] = vr[k8];
#pragma unroll
    for (int k8 = 0; k8 < 8; ++k8) {
        *(u16x4*)&V_sh[t][k8 * 8]     = { vreg[k8][0], vreg[k8][1], vreg[k8][2], vreg[k8][3] };
        *(u16x4*)&V_sh[t][k8 * 8 + 4] = { vreg[k8][4], vreg[k8][5], vreg[k8][6], vreg[k8][7] };
    }
    float krow[64];
#pragma unroll
    for (int k8 = 0; k8 < 8; ++k8) {
        u16x8 kv = kr[k8];
#pragma unroll
        for (int e = 0; e < 8; ++e) krow[k8 * 8 + e] = bf2f(kv[e]);
    }
    __syncthreads();

    for (int rr = 0; rr < uu; ++rr) {
        const float4* qp = (const float4*)q_sh[rr];
        float acc = 0.f;
#pragma unroll
        for (int i4 = 0; i4 < 16; ++i4) {
            float4 q4 = qp[i4];
            acc += q4.x * krow[i4 * 4] + q4.y * krow[i4 * 4 + 1] +
                   q4.z * krow[i4 * 4 + 2] + q4.w * krow[i4 * 4 + 3];
        }
        w_sh[rr][t] = acc;
    }
    __syncthreads();

    for (int rr = wave; rr < uu; rr += 4) {
        float4 wv = *(const float4*)&w_sh[rr][lane * 4];
        float m4 = fmaxf(fmaxf(wv.x, wv.y), fmaxf(wv.z, wv.w));
#pragma unroll
        for (int off = 16; off > 0; off >>= 1) m4 = fmaxf(m4, __shfl_xor(m4, off));
        float e0 = expf(wv.x - m4), e1 = expf(wv.y - m4);
        float e2 = expf(wv.z - m4), e3 = expf(wv.w - m4);
        float s = e0 + e1 + e2 + e3;
#pragma unroll
        for (int off = 16; off > 0; off >>= 1) s += __shfl_xor(s, off);
        float4 ev = { e0, e1, e2, e3 };
        *(float4*)&w_sh[rr][lane * 4] = ev;
        if ((lane & 31) == 0) { int jh = lane >> 5; mc_sh[rr][jh] = m4; Sc_sh[rr][jh] = s; }
    }
    __syncthreads();

    int jh = t >> 7, tt = t & 127, dp = tt & 31;
    for (int rr = tt >> 5; rr < uu; rr += 4) {
        float o0 = 0.f, o1 = 0.f;
        int j0 = jh * 128;
        for (int j = j0; j < j0 + 128; j += 4) {
            float4 w4 = *(const float4*)&w_sh[rr][j];
#pragma unroll
            for (int jj = 0; jj < 4; ++jj) {
                unsigned v = *(const unsigned*)&V_sh[j + jj][dp * 2];
                float w1 = jj == 0 ? w4.x : (jj == 1 ? w4.y : (jj == 2 ? w4.z : w4.w));
                o0 += w1 * __uint_as_float(v << 16);
                o1 += w1 * __uint_as_float(v & 0xffff0000u);
            }
        }
        float* pp = part + (((size_t)pair * 10 + rr) * 64 + chunk * 2 + jh) * 66;
        float2 o2 = { o0, o1 };
        *(float2*)&pp[2 + dp * 2] = o2;
        if (dp == 0) { pp[0] = mc_sh[rr][jh]; pp[1] = Sc_sh[rr][jh]; }
    }
}

// ---------------- output: broadcast bias ----------------
__global__ void k_bias(const float* __restrict__ bo, float* __restrict__ out) {
    size_t i = (size_t)blockIdx.x * 256 + threadIdx.x;   // 8388608 float4s
    int col4 = (int)(i & 255);
    ((float4*)out)[i] = ((const float4*)bo)[col4];
}

// ---------------- fused merge + sparse scatter ----------------
__global__ __launch_bounds__(256) void k_mergescatter(
    const float* __restrict__ part, const int* __restrict__ sel,
    const int* __restrict__ u, const float* __restrict__ wo,
    float* __restrict__ out)
{
    int idx = blockIdx.x; int pair = idx / 10; int r = idx % 10;
    int b = pair >> 4, h = pair & 15;
    if (r >= u[b]) return;
    int t = threadIdx.x;
    __shared__ float a_sh[64];
    if (t < 64) {
        const float* base = part + ((size_t)pair * 10 + r) * 64 * 66;
        float m = -1e30f;
        for (int c = 0; c < 64; ++c) m = fmaxf(m, base[c * 66]);
        float S = 0, o = 0;
        for (int c = 0; c < 64; ++c) {
            float f = expf(base[c * 66] - m);
            S += f * base[c * 66 + 1];
            o += f * base[c * 66 + 2 + t];
        }
        a_sh[t] = o / S;
    }
    __syncthreads();
    int l = sel[pair * 10 + r];
    float* orow = out + ((size_t)b * 8192 + l) * 1024;
    for (int j = t; j < 1024; j += 256) {
        const float* wr = wo + (size_t)j * 1024 + h * 64;
        float acc = 0;
#pragma unroll
        for (int d = 0; d < 64; d += 4) {
            float4 w4 = *(const float4*)(wr + d);
            acc += a_sh[d] * w4.x + a_sh[d + 1] * w4.y + a_sh[d + 2] * w4.z + a_sh[d + 3] * w4.w;
        }
        atomicAdd(orow + j, acc);
    }
}

// ---------------- workspace layout ----------------
static constexpr size_t OFF_XB    = 0;                        // 67108864
static constexpr size_t OFF_WB    = OFF_XB + 67108864;        // 6291456
static constexpr size_t OFF_KB    = OFF_WB + 6291456;         // 67108864
static constexpr size_t OFF_VB    = OFF_KB + 67108864;        // 67108864
static constexpr size_t OFF_SC    = OFF_VB + 67108864;        // 2097152
static constexpr size_t OFF_U     = OFF_SC + 2097152;         // 256
static constexpr size_t OFF_SEL   = OFF_U + 256;              // 4096
static constexpr size_t OFF_SELQ  = OFF_SEL + 4096;           // 163840
static constexpr size_t OFF_PART  = OFF_SELQ + 163840;        // 64*10*64*66*4 = 10813440
static constexpr size_t OFF_CAND  = OFF_PART + 10813440;      // 4096
static constexpr size_t OFF_CSC   = OFF_CAND + 4096;          // 8192
static constexpr size_t OFF_CQ    = OFF_CSC + 8192;           // 262144
static constexpr size_t WS_NEED   = OFF_CQ + 262144;

extern "C" void kernel_launch(void* const* d_in, const int* in_sizes, int n_in,
                              void* d_out, int out_size, void* d_ws, size_t ws_size,
                              hipStream_t stream)
{
    const float* x  = (const float*)d_in[0];
    const float* wq = (const float*)d_in[1];
    const float* bq = (const float*)d_in[2];
    const float* wk = (const float*)d_in[3];
    const float* bk = (const float*)d_in[4];
    const float* wv = (const float*)d_in[5];
    const float* bv = (const float*)d_in[6];
    const float* wo = (const float*)d_in[7];
    const float* bo = (const float*)d_in[8];
    float* out = (float*)d_out;

    if (ws_size < WS_NEED) return;

    char* ws = (char*)d_ws;
    unsigned short* xb = (unsigned short*)(ws + OFF_XB);
    unsigned short* wb = (unsigned short*)(ws + OFF_WB);
    unsigned short* Kb = (unsigned short*)(ws + OFF_KB);
    unsigned short* Vb = (unsigned short*)(ws + OFF_VB);
    float*  scores = (float*)(ws + OFF_SC);
    int*    u      = (int*)(ws + OFF_U);
    int*    sel    = (int*)(ws + OFF_SEL);
    float*  selq   = (float*)(ws + OFF_SELQ);
    float*  part   = (float*)(ws + OFF_PART);
    int*    cand   = (int*)(ws + OFF_CAND);
    double* cscore = (double*)(ws + OFF_CSC);
    float*  cq     = (float*)(ws + OFF_CQ);

    k_conv        <<<35840, 256,  0, stream>>>(x, wq, wk, wv, xb, wb);
    k_gemm_qkv    <<<6144,  256,  0, stream>>>(xb, wb, bq, bk, bv, Kb, Vb, scores);
    k_cand        <<<64,    1024, 0, stream>>>(scores, cand, u);
    k_rescore     <<<1024,  256,  0, stream>>>(cand, x, wq, bq, cscore, cq);
    k_select      <<<64,    64,   0, stream>>>(cand, cscore, cq, sel, selq);
    k_attn_part   <<<2048,  256,  0, stream>>>(Kb, Vb, selq, u, part);
    k_bias        <<<32768, 256,  0, stream>>>(bo, out);
    k_mergescatter<<<640,   256,  0, stream>>>(part, sel, u, wo, out);
}